// Round 5
// baseline (545.187 us; speedup 1.0000x reference)
//
#include <hip/hip_runtime.h>

#define N_NODES 50000
#define N_EDGES 800000
#define DIM     200
#define NBLK    100   // B blocks of S=2
#define NB_SCAN 196   // ceil(N_NODES/256)
#define KPAD    224   // DIM padded to 7*32
#define NROWPAD 50048
#define NFRAG   (7 * 14 * 64)   // fragment-packed weight: 7 nt x 14 ks x 64 lanes (x8 bf16)

typedef __attribute__((ext_vector_type(8)))  short short8;
typedef __attribute__((ext_vector_type(16))) float f32x16;

__device__ __forceinline__ unsigned short f2bf(float f) {
    unsigned u = __float_as_uint(f);
    u += 0x7fffu + ((u >> 16) & 1u);        // RNE (inputs finite)
    return (unsigned short)(u >> 16);
}

__device__ __forceinline__ float tanh_fast(float x) {
    float xa = fminf(fmaxf(x, -15.0f), 15.0f);
    float e = __expf(2.0f * xa);
    return (e - 1.0f) / (e + 1.0f);
}

__device__ __forceinline__ int uread(int v, int l) {
    return __builtin_amdgcn_readlane(v, l);
}

// ---------------------------------------------------------------- CSR build
__global__ void deg_int_kernel(const int* __restrict__ dst, int* __restrict__ degi) {
    int e = blockIdx.x * blockDim.x + threadIdx.x;
    if (e < N_EDGES) atomicAdd(&degi[dst[e]], 1);
}

__global__ __launch_bounds__(256) void scanA(const int* __restrict__ degi,
                                             int* __restrict__ pos,
                                             int* __restrict__ bsum) {
    __shared__ int tmp[256];
    int t = threadIdx.x;
    int g = blockIdx.x * 256 + t;
    int v = (g < N_NODES) ? degi[g] : 0;
    tmp[t] = v;
    __syncthreads();
    for (int off = 1; off < 256; off <<= 1) {
        int xv = (t >= off) ? tmp[t - off] : 0;
        __syncthreads();
        tmp[t] += xv;
        __syncthreads();
    }
    if (g < N_NODES) pos[g] = tmp[t] - v;
    if (t == 255) bsum[blockIdx.x] = tmp[255];
}

__global__ __launch_bounds__(256) void scanB(int* __restrict__ bsum) {
    __shared__ int tmp[256];
    int t = threadIdx.x;
    int v = (t < NB_SCAN) ? bsum[t] : 0;
    tmp[t] = v;
    __syncthreads();
    for (int off = 1; off < 256; off <<= 1) {
        int xv = (t >= off) ? tmp[t - off] : 0;
        __syncthreads();
        tmp[t] += xv;
        __syncthreads();
    }
    if (t < NB_SCAN) bsum[t] = tmp[t] - v;
}

__global__ __launch_bounds__(256) void scanC(int* __restrict__ pos, const int* __restrict__ bsum) {
    int g = blockIdx.x * 256 + threadIdx.x;
    if (g < N_NODES) pos[g] += bsum[blockIdx.x];
}

__global__ void fill_kernel(const int* __restrict__ src, const int* __restrict__ dst,
                            const int* __restrict__ et,
                            int* __restrict__ pos, int2* __restrict__ se) {
    int e = blockIdx.x * blockDim.x + threadIdx.x;
    if (e < N_EDGES) {
        int d = dst[e];
        int slot = atomicAdd(&pos[d], 1);
        se[slot] = make_int2(src[e], et[e]);
    }
}

// ---------------------------------------------------------------- weight prep (fragment-packed bf16)
// B-frag element j of lane l for (nt,ks): B[k0+j][n], n = nt*32+(l&31), k0 = ks*16+(l>>5)*8
// fragT: B[k][n] = w[k*DIM+n]   (for x @ w)
__global__ void prep_fragT(const float* __restrict__ w, unsigned short* __restrict__ o) {
    int idx = blockIdx.x * blockDim.x + threadIdx.x;
    if (idx >= NFRAG) return;
    int l = idx & 63;
    int ks = (idx >> 6) % 14;
    int nt = idx / (14 * 64);
    int n  = nt * 32 + (l & 31);
    int k0 = ks * 16 + (l >> 5) * 8;
    unsigned short v[8];
    #pragma unroll
    for (int j = 0; j < 8; ++j) {
        int k = k0 + j;
        v[j] = f2bf((n < DIM && k < DIM) ? w[k * DIM + n] : 0.0f);
    }
    *(uint4*)(o + (size_t)idx * 8) = *(uint4*)v;
}
// frag: B[k][n] = w[n*DIM+k]   (for x @ w^T)
__global__ void prep_frag(const float* __restrict__ w, unsigned short* __restrict__ o) {
    int idx = blockIdx.x * blockDim.x + threadIdx.x;
    if (idx >= NFRAG) return;
    int l = idx & 63;
    int ks = (idx >> 6) % 14;
    int nt = idx / (14 * 64);
    int n  = nt * 32 + (l & 31);
    int k0 = ks * 16 + (l >> 5) * 8;
    unsigned short v[8];
    #pragma unroll
    for (int j = 0; j < 8; ++j) {
        int k = k0 + j;
        v[j] = f2bf((n < DIM && k < DIM) ? w[n * DIM + k] : 0.0f);
    }
    *(uint4*)(o + (size_t)idx * 8) = *(uint4*)v;
}

// ---------------------------------------------------------------- pipelined gather (fp32 features)
#define GLOAD_F32(QQ, X0, X1, W0, W1)                                   \
    { int s_ = uread(sv, (QQ)); int r_ = uread(rv, (QQ));               \
      const float* xr_ = x + (size_t)s_ * DIM;                          \
      const float* wr_ = w + (size_t)r_ * (NBLK * 4);                   \
      X0 = *(const float2*)(xr_ + 2 * b0);                              \
      W0 = *(const float4*)(wr_ + 4 * b0);                              \
      if (has1) { X1 = *(const float2*)(xr_ + 2 * b1);                  \
                  W1 = *(const float4*)(wr_ + 4 * b1); } }

__global__ __launch_bounds__(256) void gatherP_f32(
        const float* __restrict__ x,
        const int2*  __restrict__ se,
        const int*   __restrict__ endpos,
        const int*   __restrict__ degi,
        const float* __restrict__ w,
        float*       __restrict__ agg) {
    int node = (blockIdx.x * blockDim.x + threadIdx.x) >> 6;
    int lane = threadIdx.x & 63;
    if (node >= N_NODES) return;
    int deg   = __builtin_amdgcn_readfirstlane(degi[node]);
    int end   = __builtin_amdgcn_readfirstlane(endpos[node]);
    int start = end - deg;
    const int b0 = lane, b1 = lane + 64;
    const bool has1 = (lane < NBLK - 64);
    float a00 = 0.f, a01 = 0.f, a10 = 0.f, a11 = 0.f;
    float c00 = 0.f, c01 = 0.f, c10 = 0.f, c11 = 0.f;

    for (int base = start; base < end; base += 64) {
        int cnt = end - base; if (cnt > 64) cnt = 64;
        int2 sei = se[base + (lane < cnt ? lane : cnt - 1)];
        int sv = sei.x, rv = sei.y;

        float2 xA0 = {0,0}, xA1 = {0,0}, xB0 = {0,0}, xB1 = {0,0};
        float4 wA0 = {0,0,0,0}, wA1 = {0,0,0,0}, wB0 = {0,0,0,0}, wB1 = {0,0,0,0};
        float2 xN0, xN1, xM0, xM1;
        float4 wN0, wN1, wM0, wM1;

        GLOAD_F32(0, xA0, xA1, wA0, wA1);
        if (cnt > 1) GLOAD_F32(1, xB0, xB1, wB0, wB1);

        for (int q = 0; q < cnt; q += 2) {
            if (q + 2 < cnt) {
                GLOAD_F32(q + 2, xN0, xN1, wN0, wN1);
                if (q + 3 < cnt) GLOAD_F32(q + 3, xM0, xM1, wM0, wM1);
            }
            a00 += xA0.x * wA0.x + xA0.y * wA0.z;
            a01 += xA0.x * wA0.y + xA0.y * wA0.w;
            if (has1) {
                a10 += xA1.x * wA1.x + xA1.y * wA1.z;
                a11 += xA1.x * wA1.y + xA1.y * wA1.w;
            }
            if (q + 1 < cnt) {
                c00 += xB0.x * wB0.x + xB0.y * wB0.z;
                c01 += xB0.x * wB0.y + xB0.y * wB0.w;
                if (has1) {
                    c10 += xB1.x * wB1.x + xB1.y * wB1.z;
                    c11 += xB1.x * wB1.y + xB1.y * wB1.w;
                }
            }
            xA0 = xN0; xA1 = xN1; wA0 = wN0; wA1 = wN1;
            xB0 = xM0; xB1 = xM1; wB0 = wM0; wB1 = wM1;
        }
    }
    float nrm = (deg > 0) ? 1.0f / (float)deg : 0.0f;
    float* ar = agg + (size_t)node * DIM;
    *(float2*)(ar + 2 * b0) = make_float2((a00 + c00) * nrm, (a01 + c01) * nrm);
    if (has1) *(float2*)(ar + 2 * b1) = make_float2((a10 + c10) * nrm, (a11 + c11) * nrm);
}

// ---------------------------------------------------------------- pipelined gather (bf16 features, stride KPAD)
#define GLOAD_BF16(QQ, U0, U1, W0, W1)                                  \
    { int s_ = uread(sv, (QQ)); int r_ = uread(rv, (QQ));               \
      const unsigned short* xr_ = x + (size_t)s_ * KPAD;                \
      const float* wr_ = w + (size_t)r_ * (NBLK * 4);                   \
      U0 = *(const unsigned*)(xr_ + 2 * b0);                            \
      W0 = *(const float4*)(wr_ + 4 * b0);                              \
      if (has1) { U1 = *(const unsigned*)(xr_ + 2 * b1);                \
                  W1 = *(const float4*)(wr_ + 4 * b1); } }

__global__ __launch_bounds__(256) void gatherP_bf16(
        const unsigned short* __restrict__ x,
        const int2*  __restrict__ se,
        const int*   __restrict__ endpos,
        const int*   __restrict__ degi,
        const float* __restrict__ w,
        float*       __restrict__ agg) {
    int node = (blockIdx.x * blockDim.x + threadIdx.x) >> 6;
    int lane = threadIdx.x & 63;
    if (node >= N_NODES) return;
    int deg   = __builtin_amdgcn_readfirstlane(degi[node]);
    int end   = __builtin_amdgcn_readfirstlane(endpos[node]);
    int start = end - deg;
    const int b0 = lane, b1 = lane + 64;
    const bool has1 = (lane < NBLK - 64);
    float a00 = 0.f, a01 = 0.f, a10 = 0.f, a11 = 0.f;
    float c00 = 0.f, c01 = 0.f, c10 = 0.f, c11 = 0.f;

    for (int base = start; base < end; base += 64) {
        int cnt = end - base; if (cnt > 64) cnt = 64;
        int2 sei = se[base + (lane < cnt ? lane : cnt - 1)];
        int sv = sei.x, rv = sei.y;

        unsigned uA0 = 0, uA1 = 0, uB0 = 0, uB1 = 0;
        float4 wA0 = {0,0,0,0}, wA1 = {0,0,0,0}, wB0 = {0,0,0,0}, wB1 = {0,0,0,0};
        unsigned uN0, uN1, uM0, uM1;
        float4 wN0, wN1, wM0, wM1;

        GLOAD_BF16(0, uA0, uA1, wA0, wA1);
        if (cnt > 1) GLOAD_BF16(1, uB0, uB1, wB0, wB1);

        for (int q = 0; q < cnt; q += 2) {
            if (q + 2 < cnt) {
                GLOAD_BF16(q + 2, uN0, uN1, wN0, wN1);
                if (q + 3 < cnt) GLOAD_BF16(q + 3, uM0, uM1, wM0, wM1);
            }
            {
                float x0 = __uint_as_float(uA0 << 16);
                float x1 = __uint_as_float(uA0 & 0xffff0000u);
                a00 += x0 * wA0.x + x1 * wA0.z;
                a01 += x0 * wA0.y + x1 * wA0.w;
                if (has1) {
                    float x2 = __uint_as_float(uA1 << 16);
                    float x3 = __uint_as_float(uA1 & 0xffff0000u);
                    a10 += x2 * wA1.x + x3 * wA1.z;
                    a11 += x2 * wA1.y + x3 * wA1.w;
                }
            }
            if (q + 1 < cnt) {
                float x0 = __uint_as_float(uB0 << 16);
                float x1 = __uint_as_float(uB0 & 0xffff0000u);
                c00 += x0 * wB0.x + x1 * wB0.z;
                c01 += x0 * wB0.y + x1 * wB0.w;
                if (has1) {
                    float x2 = __uint_as_float(uB1 << 16);
                    float x3 = __uint_as_float(uB1 & 0xffff0000u);
                    c10 += x2 * wB1.x + x3 * wB1.z;
                    c11 += x2 * wB1.y + x3 * wB1.w;
                }
            }
            uA0 = uN0; uA1 = uN1; wA0 = wN0; wA1 = wN1;
            uB0 = uM0; uB1 = uM1; wB0 = wM0; wB1 = wM1;
        }
    }
    float nrm = (deg > 0) ? 1.0f / (float)deg : 0.0f;
    float* ar = agg + (size_t)node * DIM;
    *(float2*)(ar + 2 * b0) = make_float2((a00 + c00) * nrm, (a01 + c01) * nrm);
    if (has1) *(float2*)(ar + 2 * b1) = make_float2((a10 + c10) * nrm, (a11 + c11) * nrm);
}

// ---------------------------------------------------------------- LDS staging helpers (448B-stride XOR swizzle)
#define SWZ(rr, off) ((unsigned)((rr) * (KPAD * 2) + (off)) ^ ((unsigned)((rr) & 15) << 4))

// ---------------------------------------------------------------- GEMM1: hb = bf16(tanh(agg1 + x@loop_w1 + b1))
// 128 threads = 2 waves per 32-row tile; A staged fp32->bf16 in LDS, B fragment-packed
__global__ __launch_bounds__(128) void gemm1_kernel(
        const float* __restrict__ x,
        const float* __restrict__ agg1,
        const float* __restrict__ b1,
        const unsigned short* __restrict__ w1f,   // fragment-packed loop_w1 (x@w)
        unsigned short* __restrict__ hb) {
    __shared__ __align__(16) unsigned short s_a[32 * KPAD];
    int row0 = blockIdx.x * 32;
    int tid = threadIdx.x;
    // stage x (fp32 -> bf16), swizzled; cols 0..199
    for (int i = tid; i < 32 * 100; i += 128) {
        int rr = i / 100, cc = i % 100;     // cc in float2 units
        int gr = row0 + rr;
        float2 v = (gr < N_NODES) ? *(const float2*)(x + (size_t)gr * DIM + cc * 2)
                                  : make_float2(0.f, 0.f);
        unsigned pk = (unsigned)f2bf(v.x) | ((unsigned)f2bf(v.y) << 16);
        *(unsigned*)((char*)s_a + SWZ(rr, cc * 4)) = pk;
    }
    // zero pad cols 200..223
    for (int i = tid; i < 32 * 12; i += 128) {
        int rr = i / 12, cc = i % 12;
        *(unsigned*)((char*)s_a + SWZ(rr, 400 + cc * 4)) = 0;
    }
    __syncthreads();

    int l = tid & 63, wvid = tid >> 6;
    int rl = l & 31, hl = l >> 5;
    int ntlo = wvid * 4;
    f32x16 acc[4] = {};
    for (int ks = 0; ks < 13; ++ks) {
        int k0 = ks * 16 + hl * 8;
        short8 af = *(const short8*)((const char*)s_a + SWZ(rl, k0 * 2));
        const unsigned short* wp = w1f + ((size_t)ntlo * 14 + ks) * 512 + l * 8;
        #pragma unroll
        for (int t = 0; t < 4; ++t) {
            if (ntlo + t < 7) {
                short8 bf = *(const short8*)(wp + t * 14 * 512);
                acc[t] = __builtin_amdgcn_mfma_f32_32x32x16_bf16(af, bf, acc[t], 0, 0, 0);
            }
        }
    }
    #pragma unroll
    for (int t = 0; t < 4; ++t) {
        if (ntlo + t >= 7) continue;
        int gc = (ntlo + t) * 32 + rl;
        float bias = (gc < DIM) ? b1[gc] : 0.0f;
        #pragma unroll
        for (int r = 0; r < 16; ++r) {
            int gr = row0 + (r & 3) + 8 * (r >> 2) + 4 * hl;
            float v = 0.0f;
            if (gc < DIM && gr < N_NODES)
                v = acc[t][r] + agg1[(size_t)gr * DIM + gc] + bias;
            hb[(size_t)gr * KPAD + gc] = f2bf(tanh_fast(v));
        }
    }
}

// ---------------------------------------------------------------- GEMM2 (fused RNN), 2 waves/tile
// phase A: t = agg2 + hb@loop_w2 + b2 (A staged from hb) -> t_lds
// phase B: out = tanh(t@W_ih^T + h0@W_hh^T + biases) (h0 staged fp32->bf16)
__global__ __launch_bounds__(128) void gemm2_kernel(
        const unsigned short* __restrict__ hb,
        const float* __restrict__ agg2,
        const float* __restrict__ b2,
        const unsigned short* __restrict__ w2f,   // frag-packed loop_w2 (x@w)
        const float* __restrict__ h0,
        const unsigned short* __restrict__ wihf,  // frag-packed W_ih (x@w^T)
        const unsigned short* __restrict__ whhf,  // frag-packed W_hh (x@w^T)
        const float* __restrict__ b_ih,
        const float* __restrict__ b_hh,
        float* __restrict__ out) {
    __shared__ __align__(16) unsigned short t_lds[32 * KPAD];
    __shared__ __align__(16) unsigned short s_a[32 * KPAD];
    int row0 = blockIdx.x * 32;
    int tid = threadIdx.x;
    int l = tid & 63, wvid = tid >> 6;
    int rl = l & 31, hl = l >> 5;
    int ntlo = wvid * 4;

    // stage hb tile (bf16, already padded), swizzled, 16B chunks
    for (int i = tid; i < 32 * 28; i += 128) {
        int rr = i / 28, cc = i % 28;
        uint4 v = *(const uint4*)(hb + (size_t)(row0 + rr) * KPAD + cc * 8);
        *(uint4*)((char*)s_a + SWZ(rr, cc * 16)) = v;
    }
    __syncthreads();

    // ---- phase A
    {
        f32x16 acc[4] = {};
        for (int ks = 0; ks < 13; ++ks) {
            int k0 = ks * 16 + hl * 8;
            short8 af = *(const short8*)((const char*)s_a + SWZ(rl, k0 * 2));
            const unsigned short* wp = w2f + ((size_t)ntlo * 14 + ks) * 512 + l * 8;
            #pragma unroll
            for (int t = 0; t < 4; ++t) {
                if (ntlo + t < 7) {
                    short8 bf = *(const short8*)(wp + t * 14 * 512);
                    acc[t] = __builtin_amdgcn_mfma_f32_32x32x16_bf16(af, bf, acc[t], 0, 0, 0);
                }
            }
        }
        #pragma unroll
        for (int t = 0; t < 4; ++t) {
            if (ntlo + t >= 7) continue;
            int gc = (ntlo + t) * 32 + rl;
            float bias = (gc < DIM) ? b2[gc] : 0.0f;
            #pragma unroll
            for (int r = 0; r < 16; ++r) {
                int lr = (r & 3) + 8 * (r >> 2) + 4 * hl;
                int gr = row0 + lr;
                float v = 0.0f;
                if (gc < DIM) {
                    v = acc[t][r] + bias;
                    if (gr < N_NODES) v += agg2[(size_t)gr * DIM + gc];
                }
                *(unsigned short*)((char*)t_lds + SWZ(lr, gc * 2)) = f2bf(v);
            }
        }
    }
    __syncthreads();

    // restage s_a <- h0 (fp32 -> bf16), swizzled
    for (int i = tid; i < 32 * 100; i += 128) {
        int rr = i / 100, cc = i % 100;
        int gr = row0 + rr;
        float2 v = (gr < N_NODES) ? *(const float2*)(h0 + (size_t)gr * DIM + cc * 2)
                                  : make_float2(0.f, 0.f);
        unsigned pk = (unsigned)f2bf(v.x) | ((unsigned)f2bf(v.y) << 16);
        *(unsigned*)((char*)s_a + SWZ(rr, cc * 4)) = pk;
    }
    for (int i = tid; i < 32 * 12; i += 128) {
        int rr = i / 12, cc = i % 12;
        *(unsigned*)((char*)s_a + SWZ(rr, 400 + cc * 4)) = 0;
    }
    __syncthreads();

    // ---- phase B
    f32x16 o[4] = {};
    for (int ks = 0; ks < 13; ++ks) {
        int k0 = ks * 16 + hl * 8;
        short8 tf = *(const short8*)((const char*)t_lds + SWZ(rl, k0 * 2));
        short8 hf = *(const short8*)((const char*)s_a  + SWZ(rl, k0 * 2));
        const unsigned short* wp1 = wihf + ((size_t)ntlo * 14 + ks) * 512 + l * 8;
        const unsigned short* wp2 = whhf + ((size_t)ntlo * 14 + ks) * 512 + l * 8;
        #pragma unroll
        for (int t = 0; t < 4; ++t) {
            if (ntlo + t < 7) {
                short8 bf1 = *(const short8*)(wp1 + t * 14 * 512);
                o[t] = __builtin_amdgcn_mfma_f32_32x32x16_bf16(tf, bf1, o[t], 0, 0, 0);
                short8 bf2 = *(const short8*)(wp2 + t * 14 * 512);
                o[t] = __builtin_amdgcn_mfma_f32_32x32x16_bf16(hf, bf2, o[t], 0, 0, 0);
            }
        }
    }
    #pragma unroll
    for (int t = 0; t < 4; ++t) {
        if (ntlo + t >= 7) continue;
        int gc = (ntlo + t) * 32 + rl;
        if (gc >= DIM) continue;
        float bias = b_ih[gc] + b_hh[gc];
        #pragma unroll
        for (int r = 0; r < 16; ++r) {
            int gr = row0 + (r & 3) + 8 * (r >> 2) + 4 * hl;
            if (gr < N_NODES)
                out[(size_t)gr * DIM + gc] = tanh_fast(o[t][r] + bias);
        }
    }
}

// ---------------------------------------------------------------- launch
extern "C" void kernel_launch(void* const* d_in, const int* in_sizes, int n_in,
                              void* d_out, int out_size, void* d_ws, size_t ws_size,
                              hipStream_t stream) {
    const float* node_feat = (const float*)d_in[0];
    const float* dyn_emb   = (const float*)d_in[1];
    const int*   src       = (const int*)  d_in[2];
    const int*   dst       = (const int*)  d_in[3];
    const int*   etypes    = (const int*)  d_in[4];
    const float* w1        = (const float*)d_in[5];
    const float* loop_w1   = (const float*)d_in[6];
    const float* b1        = (const float*)d_in[7];
    const float* w2        = (const float*)d_in[8];
    const float* loop_w2   = (const float*)d_in[9];
    const float* b2        = (const float*)d_in[10];
    const float* W_ih      = (const float*)d_in[11];
    const float* W_hh      = (const float*)d_in[12];
    const float* b_ih      = (const float*)d_in[13];
    const float* b_hh      = (const float*)d_in[14];
    float* out = (float*)d_out;

    // workspace layout (16B-aligned sections)
    int*   degi = (int*)d_ws;                          // 51200
    int*   pos  = degi + 51200;                        // 51200
    int*   bsum = pos  + 51200;                        // 256
    int2*  se   = (int2*)(bsum + 256);                 // 800000 int2 (6.4 MB)
    float* agg  = (float*)(se + N_EDGES);              // N*D fp32 (40 MB)
    unsigned short* hb   = (unsigned short*)(agg + (size_t)N_NODES * DIM); // 50048*224
    unsigned short* w1f  = hb   + (size_t)NROWPAD * KPAD;   // NFRAG*8 each
    unsigned short* w2f  = w1f  + (size_t)NFRAG * 8;
    unsigned short* wihf = w2f  + (size_t)NFRAG * 8;
    unsigned short* whhf = wihf + (size_t)NFRAG * 8;

    hipMemsetAsync(degi, 0, 51200 * sizeof(int), stream);

    // CSR build
    deg_int_kernel<<<(N_EDGES + 255) / 256, 256, 0, stream>>>(dst, degi);
    scanA<<<NB_SCAN, 256, 0, stream>>>(degi, pos, bsum);
    scanB<<<1, 256, 0, stream>>>(bsum);
    scanC<<<NB_SCAN, 256, 0, stream>>>(pos, bsum);
    fill_kernel<<<(N_EDGES + 255) / 256, 256, 0, stream>>>(src, dst, etypes, pos, se);

    // weight prep (fragment-packed bf16)
    prep_fragT<<<(NFRAG + 255) / 256, 256, 0, stream>>>(loop_w1, w1f);
    prep_fragT<<<(NFRAG + 255) / 256, 256, 0, stream>>>(loop_w2, w2f);
    prep_frag <<<(NFRAG + 255) / 256, 256, 0, stream>>>(W_ih, wihf);
    prep_frag <<<(NFRAG + 255) / 256, 256, 0, stream>>>(W_hh, whhf);

    // ---- layer 1
    gatherP_f32<<<(N_NODES * 64 + 255) / 256, 256, 0, stream>>>(
        node_feat, se, pos, degi, w1, agg);
    gemm1_kernel<<<(N_NODES + 31) / 32, 128, 0, stream>>>(
        node_feat, agg, b1, w1f, hb);

    // ---- layer 2
    gatherP_bf16<<<(N_NODES * 64 + 255) / 256, 256, 0, stream>>>(
        hb, se, pos, degi, w2, agg);

    // ---- fused layer-2 dense + RNN cell
    gemm2_kernel<<<(N_NODES + 31) / 32, 128, 0, stream>>>(
        hb, agg, b2, w2f, dyn_emb, wihf, whhf, b_ih, b_hh, out);
}

// Round 6
// 404.161 us; speedup vs baseline: 1.3489x; 1.3489x over previous
//
#include <hip/hip_runtime.h>

#define N_NODES 50000
#define N_EDGES 800000
#define DIM     200
#define NBLK    100   // B blocks of S=2
#define NB_SCAN 196   // ceil(N_NODES/256)
#define KPAD    224   // feature-row stride (bf16 buffers)
#define KPN     256   // gemm output-column pad (8 nt of 32)
#define NROWPAD 50048
#define NFRAG8  (8 * 14 * 64)   // fragment-packed weights: 8 nt x 14 ks x 64 lanes (x8 bf16)

typedef __attribute__((ext_vector_type(8)))  short short8;
typedef __attribute__((ext_vector_type(16))) float f32x16;

__device__ __forceinline__ unsigned short f2bf(float f) {
    unsigned u = __float_as_uint(f);
    u += 0x7fffu + ((u >> 16) & 1u);        // RNE (inputs finite)
    return (unsigned short)(u >> 16);
}

__device__ __forceinline__ float tanh_fast(float x) {
    float xa = fminf(fmaxf(x, -15.0f), 15.0f);
    float e = __expf(2.0f * xa);
    return (e - 1.0f) / (e + 1.0f);
}

__device__ __forceinline__ int uread(int v, int l) {
    return __builtin_amdgcn_readlane(v, l);
}

// LDS swizzle for 512B-stride rows, 16B-granular access
#define SWZ5(rr, off) ((unsigned)((rr) * 512 + (off)) ^ ((unsigned)((rr) & 15) << 4))

// ---------------------------------------------------------------- CSR build
__global__ void deg_int_kernel(const int* __restrict__ dst, int* __restrict__ degi) {
    int e = blockIdx.x * blockDim.x + threadIdx.x;
    if (e < N_EDGES) atomicAdd(&degi[dst[e]], 1);
}

__global__ __launch_bounds__(256) void scanA(const int* __restrict__ degi,
                                             int* __restrict__ pos,
                                             int* __restrict__ bsum) {
    __shared__ int tmp[256];
    int t = threadIdx.x;
    int g = blockIdx.x * 256 + t;
    int v = (g < N_NODES) ? degi[g] : 0;
    tmp[t] = v;
    __syncthreads();
    for (int off = 1; off < 256; off <<= 1) {
        int xv = (t >= off) ? tmp[t - off] : 0;
        __syncthreads();
        tmp[t] += xv;
        __syncthreads();
    }
    if (g < N_NODES) pos[g] = tmp[t] - v;
    if (t == 255) bsum[blockIdx.x] = tmp[255];
}

__global__ __launch_bounds__(256) void scanB(int* __restrict__ bsum) {
    __shared__ int tmp[256];
    int t = threadIdx.x;
    int v = (t < NB_SCAN) ? bsum[t] : 0;
    tmp[t] = v;
    __syncthreads();
    for (int off = 1; off < 256; off <<= 1) {
        int xv = (t >= off) ? tmp[t - off] : 0;
        __syncthreads();
        tmp[t] += xv;
        __syncthreads();
    }
    if (t < NB_SCAN) bsum[t] = tmp[t] - v;
}

__global__ __launch_bounds__(256) void scanC(int* __restrict__ pos, const int* __restrict__ bsum) {
    int g = blockIdx.x * 256 + threadIdx.x;
    if (g < N_NODES) pos[g] += bsum[blockIdx.x];
}

__global__ void fill_kernel(const int* __restrict__ src, const int* __restrict__ dst,
                            const int* __restrict__ et,
                            int* __restrict__ pos, int2* __restrict__ se) {
    int e = blockIdx.x * blockDim.x + threadIdx.x;
    if (e < N_EDGES) {
        int d = dst[e];
        int slot = atomicAdd(&pos[d], 1);
        se[slot] = make_int2(src[e], et[e]);
    }
}

// ---------------------------------------------------------------- weight prep (fragment-packed bf16, 8 nt)
// B-frag element j of lane l for (nt,ks): B[k0+j][n], n = nt*32+(l&31), k0 = ks*16+(l>>5)*8
// fragT: B[k][n] = w[k*DIM+n]   (for x @ w)
__global__ void prep_fragT(const float* __restrict__ w, unsigned short* __restrict__ o) {
    int idx = blockIdx.x * blockDim.x + threadIdx.x;
    if (idx >= NFRAG8) return;
    int l = idx & 63;
    int ks = (idx >> 6) % 14;
    int nt = idx / (14 * 64);
    int n  = nt * 32 + (l & 31);
    int k0 = ks * 16 + (l >> 5) * 8;
    unsigned short v[8];
    #pragma unroll
    for (int j = 0; j < 8; ++j) {
        int k = k0 + j;
        v[j] = f2bf((n < DIM && k < DIM) ? w[k * DIM + n] : 0.0f);
    }
    *(uint4*)(o + (size_t)idx * 8) = *(uint4*)v;
}
// frag: B[k][n] = w[n*DIM+k]   (for x @ w^T)
__global__ void prep_frag(const float* __restrict__ w, unsigned short* __restrict__ o) {
    int idx = blockIdx.x * blockDim.x + threadIdx.x;
    if (idx >= NFRAG8) return;
    int l = idx & 63;
    int ks = (idx >> 6) % 14;
    int nt = idx / (14 * 64);
    int n  = nt * 32 + (l & 31);
    int k0 = ks * 16 + (l >> 5) * 8;
    unsigned short v[8];
    #pragma unroll
    for (int j = 0; j < 8; ++j) {
        int k = k0 + j;
        v[j] = f2bf((n < DIM && k < DIM) ? w[n * DIM + k] : 0.0f);
    }
    *(uint4*)(o + (size_t)idx * 8) = *(uint4*)v;
}

// ---------------------------------------------------------------- pipelined gather (fp32 features)
#define GLOAD_F32(QQ, X0, X1, W0, W1)                                   \
    { int s_ = uread(sv, (QQ)); int r_ = uread(rv, (QQ));               \
      const float* xr_ = x + (size_t)s_ * DIM;                          \
      const float* wr_ = w + (size_t)r_ * (NBLK * 4);                   \
      X0 = *(const float2*)(xr_ + 2 * b0);                              \
      W0 = *(const float4*)(wr_ + 4 * b0);                              \
      if (has1) { X1 = *(const float2*)(xr_ + 2 * b1);                  \
                  W1 = *(const float4*)(wr_ + 4 * b1); } }

__global__ __launch_bounds__(256) void gatherP_f32(
        const float* __restrict__ x,
        const int2*  __restrict__ se,
        const int*   __restrict__ endpos,
        const int*   __restrict__ degi,
        const float* __restrict__ w,
        float*       __restrict__ agg) {
    int node = (blockIdx.x * blockDim.x + threadIdx.x) >> 6;
    int lane = threadIdx.x & 63;
    if (node >= N_NODES) return;
    int deg   = __builtin_amdgcn_readfirstlane(degi[node]);
    int end   = __builtin_amdgcn_readfirstlane(endpos[node]);
    int start = end - deg;
    const int b0 = lane, b1 = lane + 64;
    const bool has1 = (lane < NBLK - 64);
    float a00 = 0.f, a01 = 0.f, a10 = 0.f, a11 = 0.f;
    float c00 = 0.f, c01 = 0.f, c10 = 0.f, c11 = 0.f;

    for (int base = start; base < end; base += 64) {
        int cnt = end - base; if (cnt > 64) cnt = 64;
        int2 sei = se[base + (lane < cnt ? lane : cnt - 1)];
        int sv = sei.x, rv = sei.y;

        float2 xA0 = {0,0}, xA1 = {0,0}, xB0 = {0,0}, xB1 = {0,0};
        float4 wA0 = {0,0,0,0}, wA1 = {0,0,0,0}, wB0 = {0,0,0,0}, wB1 = {0,0,0,0};
        float2 xN0, xN1, xM0, xM1;
        float4 wN0, wN1, wM0, wM1;

        GLOAD_F32(0, xA0, xA1, wA0, wA1);
        if (cnt > 1) GLOAD_F32(1, xB0, xB1, wB0, wB1);

        for (int q = 0; q < cnt; q += 2) {
            if (q + 2 < cnt) {
                GLOAD_F32(q + 2, xN0, xN1, wN0, wN1);
                if (q + 3 < cnt) GLOAD_F32(q + 3, xM0, xM1, wM0, wM1);
            }
            a00 += xA0.x * wA0.x + xA0.y * wA0.z;
            a01 += xA0.x * wA0.y + xA0.y * wA0.w;
            if (has1) {
                a10 += xA1.x * wA1.x + xA1.y * wA1.z;
                a11 += xA1.x * wA1.y + xA1.y * wA1.w;
            }
            if (q + 1 < cnt) {
                c00 += xB0.x * wB0.x + xB0.y * wB0.z;
                c01 += xB0.x * wB0.y + xB0.y * wB0.w;
                if (has1) {
                    c10 += xB1.x * wB1.x + xB1.y * wB1.z;
                    c11 += xB1.x * wB1.y + xB1.y * wB1.w;
                }
            }
            xA0 = xN0; xA1 = xN1; wA0 = wN0; wA1 = wN1;
            xB0 = xM0; xB1 = xM1; wB0 = wM0; wB1 = wM1;
        }
    }
    float nrm = (deg > 0) ? 1.0f / (float)deg : 0.0f;
    float* ar = agg + (size_t)node * DIM;
    *(float2*)(ar + 2 * b0) = make_float2((a00 + c00) * nrm, (a01 + c01) * nrm);
    if (has1) *(float2*)(ar + 2 * b1) = make_float2((a10 + c10) * nrm, (a11 + c11) * nrm);
}

// ---------------------------------------------------------------- pipelined gather (bf16 features, stride KPAD)
#define GLOAD_BF16(QQ, U0, U1, W0, W1)                                  \
    { int s_ = uread(sv, (QQ)); int r_ = uread(rv, (QQ));               \
      const unsigned short* xr_ = x + (size_t)s_ * KPAD;                \
      const float* wr_ = w + (size_t)r_ * (NBLK * 4);                   \
      U0 = *(const unsigned*)(xr_ + 2 * b0);                            \
      W0 = *(const float4*)(wr_ + 4 * b0);                              \
      if (has1) { U1 = *(const unsigned*)(xr_ + 2 * b1);                \
                  W1 = *(const float4*)(wr_ + 4 * b1); } }

__global__ __launch_bounds__(256) void gatherP_bf16(
        const unsigned short* __restrict__ x,
        const int2*  __restrict__ se,
        const int*   __restrict__ endpos,
        const int*   __restrict__ degi,
        const float* __restrict__ w,
        float*       __restrict__ agg) {
    int node = (blockIdx.x * blockDim.x + threadIdx.x) >> 6;
    int lane = threadIdx.x & 63;
    if (node >= N_NODES) return;
    int deg   = __builtin_amdgcn_readfirstlane(degi[node]);
    int end   = __builtin_amdgcn_readfirstlane(endpos[node]);
    int start = end - deg;
    const int b0 = lane, b1 = lane + 64;
    const bool has1 = (lane < NBLK - 64);
    float a00 = 0.f, a01 = 0.f, a10 = 0.f, a11 = 0.f;
    float c00 = 0.f, c01 = 0.f, c10 = 0.f, c11 = 0.f;

    for (int base = start; base < end; base += 64) {
        int cnt = end - base; if (cnt > 64) cnt = 64;
        int2 sei = se[base + (lane < cnt ? lane : cnt - 1)];
        int sv = sei.x, rv = sei.y;

        unsigned uA0 = 0, uA1 = 0, uB0 = 0, uB1 = 0;
        float4 wA0 = {0,0,0,0}, wA1 = {0,0,0,0}, wB0 = {0,0,0,0}, wB1 = {0,0,0,0};
        unsigned uN0, uN1, uM0, uM1;
        float4 wN0, wN1, wM0, wM1;

        GLOAD_BF16(0, uA0, uA1, wA0, wA1);
        if (cnt > 1) GLOAD_BF16(1, uB0, uB1, wB0, wB1);

        for (int q = 0; q < cnt; q += 2) {
            if (q + 2 < cnt) {
                GLOAD_BF16(q + 2, uN0, uN1, wN0, wN1);
                if (q + 3 < cnt) GLOAD_BF16(q + 3, uM0, uM1, wM0, wM1);
            }
            {
                float x0 = __uint_as_float(uA0 << 16);
                float x1 = __uint_as_float(uA0 & 0xffff0000u);
                a00 += x0 * wA0.x + x1 * wA0.z;
                a01 += x0 * wA0.y + x1 * wA0.w;
                if (has1) {
                    float x2 = __uint_as_float(uA1 << 16);
                    float x3 = __uint_as_float(uA1 & 0xffff0000u);
                    a10 += x2 * wA1.x + x3 * wA1.z;
                    a11 += x2 * wA1.y + x3 * wA1.w;
                }
            }
            if (q + 1 < cnt) {
                float x0 = __uint_as_float(uB0 << 16);
                float x1 = __uint_as_float(uB0 & 0xffff0000u);
                c00 += x0 * wB0.x + x1 * wB0.z;
                c01 += x0 * wB0.y + x1 * wB0.w;
                if (has1) {
                    float x2 = __uint_as_float(uB1 << 16);
                    float x3 = __uint_as_float(uB1 & 0xffff0000u);
                    c10 += x2 * wB1.x + x3 * wB1.z;
                    c11 += x2 * wB1.y + x3 * wB1.w;
                }
            }
            uA0 = uN0; uA1 = uN1; wA0 = wN0; wA1 = wN1;
            uB0 = uM0; uB1 = uM1; wB0 = wM0; wB1 = wM1;
        }
    }
    float nrm = (deg > 0) ? 1.0f / (float)deg : 0.0f;
    float* ar = agg + (size_t)node * DIM;
    *(float2*)(ar + 2 * b0) = make_float2((a00 + c00) * nrm, (a01 + c01) * nrm);
    if (has1) *(float2*)(ar + 2 * b1) = make_float2((a10 + c10) * nrm, (a11 + c11) * nrm);
}

// ---------------------------------------------------------------- GEMM1: hb = bf16(tanh(agg1 + x@loop_w1 + b1))
// 256 threads = 4 waves per 32-row tile; wave w owns nt {2w, 2w+1} of 8 (branch-free).
// A staged fp32->bf16 in LDS (512B-stride swizzled); B fragment-packed in global (L2).
__global__ __launch_bounds__(256) void gemm1_kernel(
        const float* __restrict__ x,
        const float* __restrict__ agg1,
        const float* __restrict__ b1,
        const unsigned short* __restrict__ w1f,   // frag-packed loop_w1 (x@w), 8 nt
        unsigned short* __restrict__ hb) {
    __shared__ __align__(16) unsigned short s_a[32 * KPN];
    int row0 = blockIdx.x * 32;
    int tid = threadIdx.x;
    // stage x (fp32 -> bf16), swizzled; cols 0..199
    for (int i = tid; i < 32 * 100; i += 256) {
        int rr = i / 100, cc = i % 100;     // cc in float2 units
        int gr = row0 + rr;
        float2 v = (gr < N_NODES) ? *(const float2*)(x + (size_t)gr * DIM + cc * 2)
                                  : make_float2(0.f, 0.f);
        unsigned pk = (unsigned)f2bf(v.x) | ((unsigned)f2bf(v.y) << 16);
        *(unsigned*)((char*)s_a + SWZ5(rr, cc * 4)) = pk;
    }
    // zero pad cols 200..255
    for (int i = tid; i < 32 * 28; i += 256) {
        int rr = i / 28, cc = i % 28;
        *(unsigned*)((char*)s_a + SWZ5(rr, 400 + cc * 4)) = 0;
    }
    __syncthreads();

    int l = tid & 63, wv = tid >> 6;
    int rl = l & 31, hl = l >> 5;
    int ntlo = wv * 2;
    const unsigned short* wb = w1f + (size_t)(ntlo * 14) * 512 + l * 8;

    f32x16 acc0 = {}, acc1 = {};
    short8 aC  = *(const short8*)((const char*)s_a + SWZ5(rl, (hl * 8) * 2));
    short8 b0C = *(const short8*)(wb);
    short8 b1C = *(const short8*)(wb + 14 * 512);
    #pragma unroll
    for (int ks = 0; ks < 13; ++ks) {
        short8 aN = {}, b0N = {}, b1N = {};
        if (ks < 12) {
            aN  = *(const short8*)((const char*)s_a + SWZ5(rl, ((ks + 1) * 16 + hl * 8) * 2));
            b0N = *(const short8*)(wb + (ks + 1) * 512);
            b1N = *(const short8*)(wb + 14 * 512 + (ks + 1) * 512);
        }
        acc0 = __builtin_amdgcn_mfma_f32_32x32x16_bf16(aC, b0C, acc0, 0, 0, 0);
        acc1 = __builtin_amdgcn_mfma_f32_32x32x16_bf16(aC, b1C, acc1, 0, 0, 0);
        aC = aN; b0C = b0N; b1C = b1N;
    }

    #pragma unroll
    for (int t = 0; t < 2; ++t) {
        f32x16 ac = t ? acc1 : acc0;
        int gc = (ntlo + t) * 32 + rl;
        if (gc >= KPAD) continue;          // cols 224..255 not stored
        float bias = (gc < DIM) ? b1[gc] : 0.0f;
        #pragma unroll
        for (int r = 0; r < 16; ++r) {
            int gr = row0 + (r & 3) + 8 * (r >> 2) + 4 * hl;
            float v = 0.0f;
            if (gc < DIM && gr < N_NODES)
                v = ac[r] + agg1[(size_t)gr * DIM + gc] + bias;
            hb[(size_t)gr * KPAD + gc] = f2bf(tanh_fast(v));
        }
    }
}

// ---------------------------------------------------------------- GEMM2 (fused RNN), 4 waves/tile, branch-free
// phase A: t = agg2 + hb@loop_w2 + b2 -> t_lds ; phase B: out = tanh(t@W_ih^T + h0@W_hh^T + biases)
__global__ __launch_bounds__(256) void gemm2_kernel(
        const unsigned short* __restrict__ hb,
        const float* __restrict__ agg2,
        const float* __restrict__ b2,
        const unsigned short* __restrict__ w2f,   // frag-packed loop_w2 (x@w), 8 nt
        const float* __restrict__ h0,
        const unsigned short* __restrict__ wihf,  // frag-packed W_ih (x@w^T), 8 nt
        const unsigned short* __restrict__ whhf,  // frag-packed W_hh (x@w^T), 8 nt
        const float* __restrict__ b_ih,
        const float* __restrict__ b_hh,
        float* __restrict__ out) {
    __shared__ __align__(16) unsigned short s_a[32 * KPN];
    __shared__ __align__(16) unsigned short t_lds[32 * KPN];
    int row0 = blockIdx.x * 32;
    int tid = threadIdx.x;
    int l = tid & 63, wv = tid >> 6;
    int rl = l & 31, hl = l >> 5;
    int ntlo = wv * 2;

    // stage hb tile (bf16, KPAD-stride), swizzled, 16B chunks + zero pad 224..255
    for (int i = tid; i < 32 * 32; i += 256) {
        int rr = i >> 5, ch = i & 31;
        uint4 v = {0, 0, 0, 0};
        if (ch < 28) v = *(const uint4*)(hb + (size_t)(row0 + rr) * KPAD + ch * 8);
        *(uint4*)((char*)s_a + SWZ5(rr, ch * 16)) = v;
    }
    __syncthreads();

    // ---- phase A
    {
        const unsigned short* wb = w2f + (size_t)(ntlo * 14) * 512 + l * 8;
        f32x16 acc0 = {}, acc1 = {};
        short8 aC  = *(const short8*)((const char*)s_a + SWZ5(rl, (hl * 8) * 2));
        short8 b0C = *(const short8*)(wb);
        short8 b1C = *(const short8*)(wb + 14 * 512);
        #pragma unroll
        for (int ks = 0; ks < 13; ++ks) {
            short8 aN = {}, b0N = {}, b1N = {};
            if (ks < 12) {
                aN  = *(const short8*)((const char*)s_a + SWZ5(rl, ((ks + 1) * 16 + hl * 8) * 2));
                b0N = *(const short8*)(wb + (ks + 1) * 512);
                b1N = *(const short8*)(wb + 14 * 512 + (ks + 1) * 512);
            }
            acc0 = __builtin_amdgcn_mfma_f32_32x32x16_bf16(aC, b0C, acc0, 0, 0, 0);
            acc1 = __builtin_amdgcn_mfma_f32_32x32x16_bf16(aC, b1C, acc1, 0, 0, 0);
            aC = aN; b0C = b0N; b1C = b1N;
        }
        #pragma unroll
        for (int t = 0; t < 2; ++t) {
            f32x16 ac = t ? acc1 : acc0;
            int gc = (ntlo + t) * 32 + rl;
            float bias = (gc < DIM) ? b2[gc] : 0.0f;
            #pragma unroll
            for (int r = 0; r < 16; ++r) {
                int lr = (r & 3) + 8 * (r >> 2) + 4 * hl;
                int gr = row0 + lr;
                float v = 0.0f;
                if (gc < DIM) {
                    v = ac[r] + bias;
                    if (gr < N_NODES) v += agg2[(size_t)gr * DIM + gc];
                }
                *(unsigned short*)((char*)t_lds + SWZ5(lr, gc * 2)) = f2bf(v);
            }
        }
    }
    __syncthreads();   // all s_a reads done, t_lds complete

    // restage s_a <- h0 (fp32 -> bf16), swizzled; cols 0..199 real, 200..255 zero
    for (int i = tid; i < 32 * 128; i += 256) {
        int rr = i >> 7, cu = i & 127;     // cu in float2/col-pair units
        int gr = row0 + rr;
        unsigned pk = 0;
        if (cu < 100 && gr < N_NODES) {
            float2 v = *(const float2*)(h0 + (size_t)gr * DIM + cu * 2);
            pk = (unsigned)f2bf(v.x) | ((unsigned)f2bf(v.y) << 16);
        }
        *(unsigned*)((char*)s_a + SWZ5(rr, cu * 4)) = pk;
    }
    __syncthreads();

    // ---- phase B
    {
        const unsigned short* wi = wihf + (size_t)(ntlo * 14) * 512 + l * 8;
        const unsigned short* wh = whhf + (size_t)(ntlo * 14) * 512 + l * 8;
        f32x16 o0 = {}, o1 = {};
        short8 tC  = *(const short8*)((const char*)t_lds + SWZ5(rl, (hl * 8) * 2));
        short8 fC  = *(const short8*)((const char*)s_a  + SWZ5(rl, (hl * 8) * 2));
        short8 i0C = *(const short8*)(wi);
        short8 i1C = *(const short8*)(wi + 14 * 512);
        short8 h0C = *(const short8*)(wh);
        short8 h1C = *(const short8*)(wh + 14 * 512);
        #pragma unroll
        for (int ks = 0; ks < 13; ++ks) {
            short8 tN = {}, fN = {}, i0N = {}, i1N = {}, h0N = {}, h1N = {};
            if (ks < 12) {
                unsigned off = ((ks + 1) * 16 + hl * 8) * 2;
                tN  = *(const short8*)((const char*)t_lds + SWZ5(rl, off));
                fN  = *(const short8*)((const char*)s_a  + SWZ5(rl, off));
                i0N = *(const short8*)(wi + (ks + 1) * 512);
                i1N = *(const short8*)(wi + 14 * 512 + (ks + 1) * 512);
                h0N = *(const short8*)(wh + (ks + 1) * 512);
                h1N = *(const short8*)(wh + 14 * 512 + (ks + 1) * 512);
            }
            o0 = __builtin_amdgcn_mfma_f32_32x32x16_bf16(tC, i0C, o0, 0, 0, 0);
            o0 = __builtin_amdgcn_mfma_f32_32x32x16_bf16(fC, h0C, o0, 0, 0, 0);
            o1 = __builtin_amdgcn_mfma_f32_32x32x16_bf16(tC, i1C, o1, 0, 0, 0);
            o1 = __builtin_amdgcn_mfma_f32_32x32x16_bf16(fC, h1C, o1, 0, 0, 0);
            tC = tN; fC = fN; i0C = i0N; i1C = i1N; h0C = h0N; h1C = h1N;
        }
        #pragma unroll
        for (int t = 0; t < 2; ++t) {
            f32x16 oc = t ? o1 : o0;
            int gc = (ntlo + t) * 32 + rl;
            if (gc >= DIM) continue;
            float bias = b_ih[gc] + b_hh[gc];
            #pragma unroll
            for (int r = 0; r < 16; ++r) {
                int gr = row0 + (r & 3) + 8 * (r >> 2) + 4 * hl;
                if (gr < N_NODES)
                    out[(size_t)gr * DIM + gc] = tanh_fast(oc[r] + bias);
            }
        }
    }
}

// ---------------------------------------------------------------- launch
extern "C" void kernel_launch(void* const* d_in, const int* in_sizes, int n_in,
                              void* d_out, int out_size, void* d_ws, size_t ws_size,
                              hipStream_t stream) {
    const float* node_feat = (const float*)d_in[0];
    const float* dyn_emb   = (const float*)d_in[1];
    const int*   src       = (const int*)  d_in[2];
    const int*   dst       = (const int*)  d_in[3];
    const int*   etypes    = (const int*)  d_in[4];
    const float* w1        = (const float*)d_in[5];
    const float* loop_w1   = (const float*)d_in[6];
    const float* b1        = (const float*)d_in[7];
    const float* w2        = (const float*)d_in[8];
    const float* loop_w2   = (const float*)d_in[9];
    const float* b2        = (const float*)d_in[10];
    const float* W_ih      = (const float*)d_in[11];
    const float* W_hh      = (const float*)d_in[12];
    const float* b_ih      = (const float*)d_in[13];
    const float* b_hh      = (const float*)d_in[14];
    float* out = (float*)d_out;

    // workspace layout (16B-aligned sections), ~73 MB total
    int*   degi = (int*)d_ws;                          // 51200
    int*   pos  = degi + 51200;                        // 51200
    int*   bsum = pos  + 51200;                        // 256
    int2*  se   = (int2*)(bsum + 256);                 // 800000 int2 (6.4 MB)
    float* agg  = (float*)(se + N_EDGES);              // N*D fp32 (40 MB)
    unsigned short* hb   = (unsigned short*)(agg + (size_t)N_NODES * DIM); // 50048*224 (22.4 MB)
    unsigned short* w1f  = hb   + (size_t)NROWPAD * KPAD;   // NFRAG8*8 each (114688 B)
    unsigned short* w2f  = w1f  + (size_t)NFRAG8 * 8;
    unsigned short* wihf = w2f  + (size_t)NFRAG8 * 8;
    unsigned short* whhf = wihf + (size_t)NFRAG8 * 8;

    hipMemsetAsync(degi, 0, 51200 * sizeof(int), stream);

    // CSR build
    deg_int_kernel<<<(N_EDGES + 255) / 256, 256, 0, stream>>>(dst, degi);
    scanA<<<NB_SCAN, 256, 0, stream>>>(degi, pos, bsum);
    scanB<<<1, 256, 0, stream>>>(bsum);
    scanC<<<NB_SCAN, 256, 0, stream>>>(pos, bsum);
    fill_kernel<<<(N_EDGES + 255) / 256, 256, 0, stream>>>(src, dst, etypes, pos, se);

    // weight prep (fragment-packed bf16, 8 nt)
    prep_fragT<<<(NFRAG8 + 255) / 256, 256, 0, stream>>>(loop_w1, w1f);
    prep_fragT<<<(NFRAG8 + 255) / 256, 256, 0, stream>>>(loop_w2, w2f);
    prep_frag <<<(NFRAG8 + 255) / 256, 256, 0, stream>>>(W_ih, wihf);
    prep_frag <<<(NFRAG8 + 255) / 256, 256, 0, stream>>>(W_hh, whhf);

    // ---- layer 1
    gatherP_f32<<<(N_NODES * 64 + 255) / 256, 256, 0, stream>>>(
        node_feat, se, pos, degi, w1, agg);
    gemm1_kernel<<<(N_NODES + 31) / 32, 256, 0, stream>>>(
        node_feat, agg, b1, w1f, hb);

    // ---- layer 2
    gatherP_bf16<<<(N_NODES * 64 + 255) / 256, 256, 0, stream>>>(
        hb, se, pos, degi, w2, agg);

    // ---- fused layer-2 dense + RNN cell
    gemm2_kernel<<<(N_NODES + 31) / 32, 256, 0, stream>>>(
        hb, agg, b2, w2f, dyn_emb, wihf, whhf, b_ih, b_hh, out);
}

// Round 7
// 374.105 us; speedup vs baseline: 1.4573x; 1.0803x over previous
//
#include <hip/hip_runtime.h>

#define N_NODES 50000
#define N_EDGES 800000
#define DIM     200
#define NBLK    100   // B blocks of S=2
#define NRELS   230
#define NB_SCAN 196   // ceil(N_NODES/256)
#define KPAD    224   // feature-row stride (bf16 buffers)
#define KPN     256   // gemm output-column pad (8 nt of 32)
#define NROWPAD 50048
#define NFRAG8  (8 * 14 * 64)   // fragment-packed weights: 8 nt x 14 ks x 64 lanes (x8 bf16)

typedef __attribute__((ext_vector_type(8)))  short short8;
typedef __attribute__((ext_vector_type(16))) float f32x16;

__device__ __forceinline__ unsigned short f2bf(float f) {
    unsigned u = __float_as_uint(f);
    u += 0x7fffu + ((u >> 16) & 1u);        // RNE (inputs finite)
    return (unsigned short)(u >> 16);
}

__device__ __forceinline__ float bflo(unsigned u) { return __uint_as_float(u << 16); }
__device__ __forceinline__ float bfhi(unsigned u) { return __uint_as_float(u & 0xffff0000u); }

__device__ __forceinline__ float tanh_fast(float x) {
    float xa = fminf(fmaxf(x, -15.0f), 15.0f);
    float e = __expf(2.0f * xa);
    return (e - 1.0f) / (e + 1.0f);
}

__device__ __forceinline__ int uread(int v, int l) {
    return __builtin_amdgcn_readlane(v, l);
}

// LDS swizzle for 512B-stride rows, 16B-granular access
#define SWZ5(rr, off) ((unsigned)((rr) * 512 + (off)) ^ ((unsigned)((rr) & 15) << 4))

// ---------------------------------------------------------------- CSR build
__global__ void deg_int_kernel(const int* __restrict__ dst, int* __restrict__ degi) {
    int e = blockIdx.x * blockDim.x + threadIdx.x;
    if (e < N_EDGES) atomicAdd(&degi[dst[e]], 1);
}

__global__ __launch_bounds__(256) void scanA(const int* __restrict__ degi,
                                             int* __restrict__ pos,
                                             int* __restrict__ bsum) {
    __shared__ int tmp[256];
    int t = threadIdx.x;
    int g = blockIdx.x * 256 + t;
    int v = (g < N_NODES) ? degi[g] : 0;
    tmp[t] = v;
    __syncthreads();
    for (int off = 1; off < 256; off <<= 1) {
        int xv = (t >= off) ? tmp[t - off] : 0;
        __syncthreads();
        tmp[t] += xv;
        __syncthreads();
    }
    if (g < N_NODES) pos[g] = tmp[t] - v;
    if (t == 255) bsum[blockIdx.x] = tmp[255];
}

__global__ __launch_bounds__(256) void scanB(int* __restrict__ bsum) {
    __shared__ int tmp[256];
    int t = threadIdx.x;
    int v = (t < NB_SCAN) ? bsum[t] : 0;
    tmp[t] = v;
    __syncthreads();
    for (int off = 1; off < 256; off <<= 1) {
        int xv = (t >= off) ? tmp[t - off] : 0;
        __syncthreads();
        tmp[t] += xv;
        __syncthreads();
    }
    if (t < NB_SCAN) bsum[t] = tmp[t] - v;
}

__global__ __launch_bounds__(256) void scanC(int* __restrict__ pos, const int* __restrict__ bsum) {
    int g = blockIdx.x * 256 + threadIdx.x;
    if (g < N_NODES) pos[g] += bsum[blockIdx.x];
}

__global__ void fill_kernel(const int* __restrict__ src, const int* __restrict__ dst,
                            const int* __restrict__ et,
                            int* __restrict__ pos, int2* __restrict__ se) {
    int e = blockIdx.x * blockDim.x + threadIdx.x;
    if (e < N_EDGES) {
        int d = dst[e];
        int slot = atomicAdd(&pos[d], 1);
        se[slot] = make_int2(src[e], et[e]);
    }
}

// ---------------------------------------------------------------- feature / relation-weight bf16 prep
// xb[row][KPAD] = bf16(node_feat[row][.]), zero-padded rows/cols
__global__ void prep_xb(const float* __restrict__ x, unsigned short* __restrict__ o) {
    int idx = blockIdx.x * blockDim.x + threadIdx.x;   // over NROWPAD * (KPAD/2)
    if (idx >= NROWPAD * (KPAD / 2)) return;
    int row = idx / (KPAD / 2), cu = idx % (KPAD / 2);
    unsigned pk = 0;
    if (row < N_NODES && cu < 100) {
        float2 v = *(const float2*)(x + (size_t)row * DIM + cu * 2);
        pk = (unsigned)f2bf(v.x) | ((unsigned)f2bf(v.y) << 16);
    }
    *(unsigned*)(o + (size_t)idx * 2) = pk;
}

// wb[r][b][0..3] = bf16(w[r][b][.][.]) packed 8B per block
__global__ void prep_wb(const float* __restrict__ w, unsigned short* __restrict__ o) {
    int idx = blockIdx.x * blockDim.x + threadIdx.x;   // over NRELS*NBLK
    if (idx >= NRELS * NBLK) return;
    float4 v = *(const float4*)(w + (size_t)idx * 4);
    unsigned lo = (unsigned)f2bf(v.x) | ((unsigned)f2bf(v.y) << 16);
    unsigned hi = (unsigned)f2bf(v.z) | ((unsigned)f2bf(v.w) << 16);
    *(uint2*)(o + (size_t)idx * 4) = make_uint2(lo, hi);
}

// ---------------------------------------------------------------- weight prep (fragment-packed bf16, 8 nt)
// fragT: B[k][n] = w[k*DIM+n]   (for x @ w)
__global__ void prep_fragT(const float* __restrict__ w, unsigned short* __restrict__ o) {
    int idx = blockIdx.x * blockDim.x + threadIdx.x;
    if (idx >= NFRAG8) return;
    int l = idx & 63;
    int ks = (idx >> 6) % 14;
    int nt = idx / (14 * 64);
    int n  = nt * 32 + (l & 31);
    int k0 = ks * 16 + (l >> 5) * 8;
    unsigned short v[8];
    #pragma unroll
    for (int j = 0; j < 8; ++j) {
        int k = k0 + j;
        v[j] = f2bf((n < DIM && k < DIM) ? w[k * DIM + n] : 0.0f);
    }
    *(uint4*)(o + (size_t)idx * 8) = *(uint4*)v;
}
// frag: B[k][n] = w[n*DIM+k]   (for x @ w^T)
__global__ void prep_frag(const float* __restrict__ w, unsigned short* __restrict__ o) {
    int idx = blockIdx.x * blockDim.x + threadIdx.x;
    if (idx >= NFRAG8) return;
    int l = idx & 63;
    int ks = (idx >> 6) % 14;
    int nt = idx / (14 * 64);
    int n  = nt * 32 + (l & 31);
    int k0 = ks * 16 + (l >> 5) * 8;
    unsigned short v[8];
    #pragma unroll
    for (int j = 0; j < 8; ++j) {
        int k = k0 + j;
        v[j] = f2bf((n < DIM && k < DIM) ? w[n * DIM + k] : 0.0f);
    }
    *(uint4*)(o + (size_t)idx * 8) = *(uint4*)v;
}

// ---------------------------------------------------------------- pipelined gather (bf16 x, bf16 w)
#define GLOADB(QQ, U0, U1, V0, V1)                                      \
    { int s_ = uread(sv, (QQ)); int r_ = uread(rv, (QQ));               \
      const unsigned short* xr_ = x + (size_t)s_ * KPAD;                \
      const unsigned short* wr_ = wb + (size_t)r_ * (NBLK * 4);         \
      U0 = *(const unsigned*)(xr_ + 2 * b0);                            \
      V0 = *(const uint2*)(wr_ + 4 * b0);                               \
      if (has1) { U1 = *(const unsigned*)(xr_ + 2 * b1);                \
                  V1 = *(const uint2*)(wr_ + 4 * b1); } }

__global__ __launch_bounds__(256) void gatherB(
        const unsigned short* __restrict__ x,    // [NROWPAD][KPAD] bf16
        const int2*  __restrict__ se,
        const int*   __restrict__ endpos,
        const int*   __restrict__ degi,
        const unsigned short* __restrict__ wb,   // [R][NBLK][4] bf16
        float*       __restrict__ agg) {
    int node = (blockIdx.x * blockDim.x + threadIdx.x) >> 6;
    int lane = threadIdx.x & 63;
    if (node >= N_NODES) return;
    int deg   = __builtin_amdgcn_readfirstlane(degi[node]);
    int end   = __builtin_amdgcn_readfirstlane(endpos[node]);
    int start = end - deg;
    const int b0 = lane, b1 = lane + 64;
    const bool has1 = (lane < NBLK - 64);
    float a00 = 0.f, a01 = 0.f, a10 = 0.f, a11 = 0.f;
    float c00 = 0.f, c01 = 0.f, c10 = 0.f, c11 = 0.f;

    for (int base = start; base < end; base += 64) {
        int cnt = end - base; if (cnt > 64) cnt = 64;
        int2 sei = se[base + (lane < cnt ? lane : cnt - 1)];
        int sv = sei.x, rv = sei.y;

        unsigned uA0 = 0, uA1 = 0, uB0 = 0, uB1 = 0;
        uint2 vA0 = {0,0}, vA1 = {0,0}, vB0 = {0,0}, vB1 = {0,0};
        unsigned uN0, uN1, uM0, uM1;
        uint2 vN0, vN1, vM0, vM1;

        GLOADB(0, uA0, uA1, vA0, vA1);
        if (cnt > 1) GLOADB(1, uB0, uB1, vB0, vB1);

        for (int q = 0; q < cnt; q += 2) {
            if (q + 2 < cnt) {
                GLOADB(q + 2, uN0, uN1, vN0, vN1);
                if (q + 3 < cnt) GLOADB(q + 3, uM0, uM1, vM0, vM1);
            }
            {
                float x0 = bflo(uA0), x1 = bfhi(uA0);
                a00 += x0 * bflo(vA0.x) + x1 * bflo(vA0.y);
                a01 += x0 * bfhi(vA0.x) + x1 * bfhi(vA0.y);
                if (has1) {
                    float x2 = bflo(uA1), x3 = bfhi(uA1);
                    a10 += x2 * bflo(vA1.x) + x3 * bflo(vA1.y);
                    a11 += x2 * bfhi(vA1.x) + x3 * bfhi(vA1.y);
                }
            }
            if (q + 1 < cnt) {
                float x0 = bflo(uB0), x1 = bfhi(uB0);
                c00 += x0 * bflo(vB0.x) + x1 * bflo(vB0.y);
                c01 += x0 * bfhi(vB0.x) + x1 * bfhi(vB0.y);
                if (has1) {
                    float x2 = bflo(uB1), x3 = bfhi(uB1);
                    c10 += x2 * bflo(vB1.x) + x3 * bflo(vB1.y);
                    c11 += x2 * bfhi(vB1.x) + x3 * bfhi(vB1.y);
                }
            }
            uA0 = uN0; uA1 = uN1; vA0 = vN0; vA1 = vN1;
            uB0 = uM0; uB1 = uM1; vB0 = vM0; vB1 = vM1;
        }
    }
    float nrm = (deg > 0) ? 1.0f / (float)deg : 0.0f;
    float* ar = agg + (size_t)node * DIM;
    *(float2*)(ar + 2 * b0) = make_float2((a00 + c00) * nrm, (a01 + c01) * nrm);
    if (has1) *(float2*)(ar + 2 * b1) = make_float2((a10 + c10) * nrm, (a11 + c11) * nrm);
}

// ---------------------------------------------------------------- GEMM1: hb = bf16(tanh(agg1 + x@loop_w1 + b1))
// In-place: xb and hb are the SAME buffer (block reads its 32 rows, then overwrites them).
__global__ __launch_bounds__(256) void gemm1_kernel(
        unsigned short* xb_hb,                    // [NROWPAD][KPAD] bf16 (no restrict: in-place)
        const float* __restrict__ agg1,
        const float* __restrict__ b1,
        const unsigned short* __restrict__ w1f) { // frag-packed loop_w1 (x@w), 8 nt
    __shared__ __align__(16) unsigned short s_a[32 * KPN];
    int row0 = blockIdx.x * 32;
    int tid = threadIdx.x;
    // stage xb tile (bf16, KPAD stride), swizzled; pad cols 224..255 zero
    for (int i = tid; i < 32 * 32; i += 256) {
        int rr = i >> 5, ch = i & 31;
        uint4 v = {0, 0, 0, 0};
        if (ch < 28) v = *(const uint4*)(xb_hb + (size_t)(row0 + rr) * KPAD + ch * 8);
        *(uint4*)((char*)s_a + SWZ5(rr, ch * 16)) = v;
    }
    __syncthreads();

    int l = tid & 63, wv = tid >> 6;
    int rl = l & 31, hl = l >> 5;
    int ntlo = wv * 2;
    const unsigned short* wb = w1f + (size_t)(ntlo * 14) * 512 + l * 8;

    f32x16 acc0 = {}, acc1 = {};
    short8 aC  = *(const short8*)((const char*)s_a + SWZ5(rl, (hl * 8) * 2));
    short8 b0C = *(const short8*)(wb);
    short8 b1C = *(const short8*)(wb + 14 * 512);
    #pragma unroll
    for (int ks = 0; ks < 13; ++ks) {
        short8 aN = {}, b0N = {}, b1N = {};
        if (ks < 12) {
            aN  = *(const short8*)((const char*)s_a + SWZ5(rl, ((ks + 1) * 16 + hl * 8) * 2));
            b0N = *(const short8*)(wb + (ks + 1) * 512);
            b1N = *(const short8*)(wb + 14 * 512 + (ks + 1) * 512);
        }
        acc0 = __builtin_amdgcn_mfma_f32_32x32x16_bf16(aC, b0C, acc0, 0, 0, 0);
        acc1 = __builtin_amdgcn_mfma_f32_32x32x16_bf16(aC, b1C, acc1, 0, 0, 0);
        aC = aN; b0C = b0N; b1C = b1N;
    }
    __syncthreads();   // all tile reads done before in-place overwrite

    #pragma unroll
    for (int t = 0; t < 2; ++t) {
        f32x16 ac = t ? acc1 : acc0;
        int gc = (ntlo + t) * 32 + rl;
        if (gc >= KPAD) continue;          // cols 224..255 not stored
        float bias = (gc < DIM) ? b1[gc] : 0.0f;
        #pragma unroll
        for (int r = 0; r < 16; ++r) {
            int gr = row0 + (r & 3) + 8 * (r >> 2) + 4 * hl;
            float v = 0.0f;
            if (gc < DIM && gr < N_NODES)
                v = ac[r] + agg1[(size_t)gr * DIM + gc] + bias;
            xb_hb[(size_t)gr * KPAD + gc] = f2bf(tanh_fast(v));
        }
    }
}

// ---------------------------------------------------------------- GEMM2 (fused RNN), 4 waves/tile, branch-free
__global__ __launch_bounds__(256) void gemm2_kernel(
        const unsigned short* __restrict__ hb,
        const float* __restrict__ agg2,
        const float* __restrict__ b2,
        const unsigned short* __restrict__ w2f,   // frag-packed loop_w2 (x@w), 8 nt
        const float* __restrict__ h0,
        const unsigned short* __restrict__ wihf,  // frag-packed W_ih (x@w^T), 8 nt
        const unsigned short* __restrict__ whhf,  // frag-packed W_hh (x@w^T), 8 nt
        const float* __restrict__ b_ih,
        const float* __restrict__ b_hh,
        float* __restrict__ out) {
    __shared__ __align__(16) unsigned short s_a[32 * KPN];
    __shared__ __align__(16) unsigned short t_lds[32 * KPN];
    int row0 = blockIdx.x * 32;
    int tid = threadIdx.x;
    int l = tid & 63, wv = tid >> 6;
    int rl = l & 31, hl = l >> 5;
    int ntlo = wv * 2;

    // stage hb tile (bf16, KPAD-stride), swizzled, 16B chunks + zero pad 224..255
    for (int i = tid; i < 32 * 32; i += 256) {
        int rr = i >> 5, ch = i & 31;
        uint4 v = {0, 0, 0, 0};
        if (ch < 28) v = *(const uint4*)(hb + (size_t)(row0 + rr) * KPAD + ch * 8);
        *(uint4*)((char*)s_a + SWZ5(rr, ch * 16)) = v;
    }
    __syncthreads();

    // ---- phase A
    {
        const unsigned short* wb = w2f + (size_t)(ntlo * 14) * 512 + l * 8;
        f32x16 acc0 = {}, acc1 = {};
        short8 aC  = *(const short8*)((const char*)s_a + SWZ5(rl, (hl * 8) * 2));
        short8 b0C = *(const short8*)(wb);
        short8 b1C = *(const short8*)(wb + 14 * 512);
        #pragma unroll
        for (int ks = 0; ks < 13; ++ks) {
            short8 aN = {}, b0N = {}, b1N = {};
            if (ks < 12) {
                aN  = *(const short8*)((const char*)s_a + SWZ5(rl, ((ks + 1) * 16 + hl * 8) * 2));
                b0N = *(const short8*)(wb + (ks + 1) * 512);
                b1N = *(const short8*)(wb + 14 * 512 + (ks + 1) * 512);
            }
            acc0 = __builtin_amdgcn_mfma_f32_32x32x16_bf16(aC, b0C, acc0, 0, 0, 0);
            acc1 = __builtin_amdgcn_mfma_f32_32x32x16_bf16(aC, b1C, acc1, 0, 0, 0);
            aC = aN; b0C = b0N; b1C = b1N;
        }
        #pragma unroll
        for (int t = 0; t < 2; ++t) {
            f32x16 ac = t ? acc1 : acc0;
            int gc = (ntlo + t) * 32 + rl;
            float bias = (gc < DIM) ? b2[gc] : 0.0f;
            #pragma unroll
            for (int r = 0; r < 16; ++r) {
                int lr = (r & 3) + 8 * (r >> 2) + 4 * hl;
                int gr = row0 + lr;
                float v = 0.0f;
                if (gc < DIM) {
                    v = ac[r] + bias;
                    if (gr < N_NODES) v += agg2[(size_t)gr * DIM + gc];
                }
                *(unsigned short*)((char*)t_lds + SWZ5(lr, gc * 2)) = f2bf(v);
            }
        }
    }
    __syncthreads();   // all s_a reads done, t_lds complete

    // restage s_a <- h0 (fp32 -> bf16), swizzled; cols 0..199 real, 200..255 zero
    for (int i = tid; i < 32 * 128; i += 256) {
        int rr = i >> 7, cu = i & 127;     // cu in float2/col-pair units
        int gr = row0 + rr;
        unsigned pk = 0;
        if (cu < 100 && gr < N_NODES) {
            float2 v = *(const float2*)(h0 + (size_t)gr * DIM + cu * 2);
            pk = (unsigned)f2bf(v.x) | ((unsigned)f2bf(v.y) << 16);
        }
        *(unsigned*)((char*)s_a + SWZ5(rr, cu * 4)) = pk;
    }
    __syncthreads();

    // ---- phase B
    {
        const unsigned short* wi = wihf + (size_t)(ntlo * 14) * 512 + l * 8;
        const unsigned short* wh = whhf + (size_t)(ntlo * 14) * 512 + l * 8;
        f32x16 o0 = {}, o1 = {};
        short8 tC  = *(const short8*)((const char*)t_lds + SWZ5(rl, (hl * 8) * 2));
        short8 fC  = *(const short8*)((const char*)s_a  + SWZ5(rl, (hl * 8) * 2));
        short8 i0C = *(const short8*)(wi);
        short8 i1C = *(const short8*)(wi + 14 * 512);
        short8 h0C = *(const short8*)(wh);
        short8 h1C = *(const short8*)(wh + 14 * 512);
        #pragma unroll
        for (int ks = 0; ks < 13; ++ks) {
            short8 tN = {}, fN = {}, i0N = {}, i1N = {}, h0N = {}, h1N = {};
            if (ks < 12) {
                unsigned off = ((ks + 1) * 16 + hl * 8) * 2;
                tN  = *(const short8*)((const char*)t_lds + SWZ5(rl, off));
                fN  = *(const short8*)((const char*)s_a  + SWZ5(rl, off));
                i0N = *(const short8*)(wi + (ks + 1) * 512);
                i1N = *(const short8*)(wi + 14 * 512 + (ks + 1) * 512);
                h0N = *(const short8*)(wh + (ks + 1) * 512);
                h1N = *(const short8*)(wh + 14 * 512 + (ks + 1) * 512);
            }
            o0 = __builtin_amdgcn_mfma_f32_32x32x16_bf16(tC, i0C, o0, 0, 0, 0);
            o0 = __builtin_amdgcn_mfma_f32_32x32x16_bf16(fC, h0C, o0, 0, 0, 0);
            o1 = __builtin_amdgcn_mfma_f32_32x32x16_bf16(tC, i1C, o1, 0, 0, 0);
            o1 = __builtin_amdgcn_mfma_f32_32x32x16_bf16(fC, h1C, o1, 0, 0, 0);
            tC = tN; fC = fN; i0C = i0N; i1C = i1N; h0C = h0N; h1C = h1N;
        }
        #pragma unroll
        for (int t = 0; t < 2; ++t) {
            f32x16 oc = t ? o1 : o0;
            int gc = (ntlo + t) * 32 + rl;
            if (gc >= DIM) continue;
            float bias = b_ih[gc] + b_hh[gc];
            #pragma unroll
            for (int r = 0; r < 16; ++r) {
                int gr = row0 + (r & 3) + 8 * (r >> 2) + 4 * hl;
                if (gr < N_NODES)
                    out[(size_t)gr * DIM + gc] = tanh_fast(oc[r] + bias);
            }
        }
    }
}

// ---------------------------------------------------------------- launch
extern "C" void kernel_launch(void* const* d_in, const int* in_sizes, int n_in,
                              void* d_out, int out_size, void* d_ws, size_t ws_size,
                              hipStream_t stream) {
    const float* node_feat = (const float*)d_in[0];
    const float* dyn_emb   = (const float*)d_in[1];
    const int*   src       = (const int*)  d_in[2];
    const int*   dst       = (const int*)  d_in[3];
    const int*   etypes    = (const int*)  d_in[4];
    const float* w1        = (const float*)d_in[5];
    const float* loop_w1   = (const float*)d_in[6];
    const float* b1        = (const float*)d_in[7];
    const float* w2        = (const float*)d_in[8];
    const float* loop_w2   = (const float*)d_in[9];
    const float* b2        = (const float*)d_in[10];
    const float* W_ih      = (const float*)d_in[11];
    const float* W_hh      = (const float*)d_in[12];
    const float* b_ih      = (const float*)d_in[13];
    const float* b_hh      = (const float*)d_in[14];
    float* out = (float*)d_out;

    // workspace layout (~71 MB)
    int*   degi = (int*)d_ws;                          // 51200
    int*   pos  = degi + 51200;                        // 51200
    int*   bsum = pos  + 51200;                        // 256
    int2*  se   = (int2*)(bsum + 256);                 // 800000 int2 (6.4 MB)
    float* agg  = (float*)(se + N_EDGES);              // N*D fp32 (40 MB)
    unsigned short* hb   = (unsigned short*)(agg + (size_t)N_NODES * DIM); // 50048*224 (22.4 MB) — ALSO xb
    unsigned short* w1f  = hb   + (size_t)NROWPAD * KPAD;   // NFRAG8*8 each
    unsigned short* w2f  = w1f  + (size_t)NFRAG8 * 8;
    unsigned short* wihf = w2f  + (size_t)NFRAG8 * 8;
    unsigned short* whhf = wihf + (size_t)NFRAG8 * 8;
    unsigned short* w1b  = whhf + (size_t)NFRAG8 * 8;       // NRELS*NBLK*4 (184 KB)
    unsigned short* w2b  = w1b  + (size_t)NRELS * NBLK * 4;

    hipMemsetAsync(degi, 0, 51200 * sizeof(int), stream);

    // CSR build
    deg_int_kernel<<<(N_EDGES + 255) / 256, 256, 0, stream>>>(dst, degi);
    scanA<<<NB_SCAN, 256, 0, stream>>>(degi, pos, bsum);
    scanB<<<1, 256, 0, stream>>>(bsum);
    scanC<<<NB_SCAN, 256, 0, stream>>>(pos, bsum);
    fill_kernel<<<(N_EDGES + 255) / 256, 256, 0, stream>>>(src, dst, etypes, pos, se);

    // bf16 prep: features, relation weights, frag-packed dense weights
    prep_xb<<<(NROWPAD * (KPAD / 2) + 255) / 256, 256, 0, stream>>>(node_feat, hb);
    prep_wb<<<(NRELS * NBLK + 255) / 256, 256, 0, stream>>>(w1, w1b);
    prep_wb<<<(NRELS * NBLK + 255) / 256, 256, 0, stream>>>(w2, w2b);
    prep_fragT<<<(NFRAG8 + 255) / 256, 256, 0, stream>>>(loop_w1, w1f);
    prep_fragT<<<(NFRAG8 + 255) / 256, 256, 0, stream>>>(loop_w2, w2f);
    prep_frag <<<(NFRAG8 + 255) / 256, 256, 0, stream>>>(W_ih, wihf);
    prep_frag <<<(NFRAG8 + 255) / 256, 256, 0, stream>>>(W_hh, whhf);

    // ---- layer 1 (gather reads xb=hb; gemm1 overwrites it in place with h)
    gatherB<<<(N_NODES * 64 + 255) / 256, 256, 0, stream>>>(
        hb, se, pos, degi, w1b, agg);
    gemm1_kernel<<<(N_NODES + 31) / 32, 256, 0, stream>>>(
        hb, agg, b1, w1f);

    // ---- layer 2
    gatherB<<<(N_NODES * 64 + 255) / 256, 256, 0, stream>>>(
        hb, se, pos, degi, w2b, agg);

    // ---- fused layer-2 dense + RNN cell
    gemm2_kernel<<<(N_NODES + 31) / 32, 256, 0, stream>>>(
        hb, agg, b2, w2f, dyn_emb, wihf, whhf, b_ih, b_hh, out);
}

// Round 8
// 351.050 us; speedup vs baseline: 1.5530x; 1.0657x over previous
//
#include <hip/hip_runtime.h>

#define N_NODES 50000
#define N_EDGES 800000
#define DIM     200
#define NBLK    100   // B blocks of S=2
#define NRELS   230
#define NB_SCAN 196   // ceil(N_NODES/256)
#define KPAD    224   // feature-row stride (bf16 buffers)
#define KPN     256   // gemm output-column pad (8 nt of 32)
#define NROWPAD 50048
#define NFRAG8  (8 * 14 * 64)   // fragment-packed weights: 8 nt x 14 ks x 64 lanes (x8 bf16)

typedef __attribute__((ext_vector_type(8)))  short short8;
typedef __attribute__((ext_vector_type(16))) float f32x16;

__device__ __forceinline__ unsigned short f2bf(float f) {
    unsigned u = __float_as_uint(f);
    u += 0x7fffu + ((u >> 16) & 1u);        // RNE (inputs finite)
    return (unsigned short)(u >> 16);
}

__device__ __forceinline__ float bflo(unsigned u) { return __uint_as_float(u << 16); }
__device__ __forceinline__ float bfhi(unsigned u) { return __uint_as_float(u & 0xffff0000u); }
__device__ __forceinline__ float b2f(unsigned short u) { return __uint_as_float((unsigned)u << 16); }

__device__ __forceinline__ float tanh_fast(float x) {
    float xa = fminf(fmaxf(x, -15.0f), 15.0f);
    float e = __expf(2.0f * xa);
    return (e - 1.0f) / (e + 1.0f);
}

__device__ __forceinline__ int uread(int v, int l) {
    return __builtin_amdgcn_readlane(v, l);
}

// LDS swizzle for 512B-stride rows, 16B-granular access
#define SWZ5(rr, off) ((unsigned)((rr) * 512 + (off)) ^ ((unsigned)((rr) & 15) << 4))

// ---------------------------------------------------------------- CSR build
__global__ void deg_int_kernel(const int* __restrict__ dst, int* __restrict__ degi) {
    int e = blockIdx.x * blockDim.x + threadIdx.x;
    if (e < N_EDGES) atomicAdd(&degi[dst[e]], 1);
}

__global__ __launch_bounds__(256) void scanA(const int* __restrict__ degi,
                                             int* __restrict__ pos,
                                             int* __restrict__ bsum) {
    __shared__ int tmp[256];
    int t = threadIdx.x;
    int g = blockIdx.x * 256 + t;
    int v = (g < N_NODES) ? degi[g] : 0;
    tmp[t] = v;
    __syncthreads();
    for (int off = 1; off < 256; off <<= 1) {
        int xv = (t >= off) ? tmp[t - off] : 0;
        __syncthreads();
        tmp[t] += xv;
        __syncthreads();
    }
    if (g < N_NODES) pos[g] = tmp[t] - v;
    if (t == 255) bsum[blockIdx.x] = tmp[255];
}

__global__ __launch_bounds__(256) void scanB(int* __restrict__ bsum) {
    __shared__ int tmp[256];
    int t = threadIdx.x;
    int v = (t < NB_SCAN) ? bsum[t] : 0;
    tmp[t] = v;
    __syncthreads();
    for (int off = 1; off < 256; off <<= 1) {
        int xv = (t >= off) ? tmp[t - off] : 0;
        __syncthreads();
        tmp[t] += xv;
        __syncthreads();
    }
    if (t < NB_SCAN) bsum[t] = tmp[t] - v;
}

__global__ __launch_bounds__(256) void scanC(int* __restrict__ pos, const int* __restrict__ bsum) {
    int g = blockIdx.x * 256 + threadIdx.x;
    if (g < N_NODES) pos[g] += bsum[blockIdx.x];
}

__global__ void fill_kernel(const int* __restrict__ src, const int* __restrict__ dst,
                            const int* __restrict__ et,
                            int* __restrict__ pos, int2* __restrict__ se) {
    int e = blockIdx.x * blockDim.x + threadIdx.x;
    if (e < N_EDGES) {
        int d = dst[e];
        int slot = atomicAdd(&pos[d], 1);
        se[slot] = make_int2(src[e], et[e]);
    }
}

// ---------------------------------------------------------------- feature / relation-weight bf16 prep
// xb[row][KPAD] = bf16(x[row][.]), zero-padded rows/cols
__global__ void prep_xb(const float* __restrict__ x, unsigned short* __restrict__ o) {
    int idx = blockIdx.x * blockDim.x + threadIdx.x;   // over NROWPAD * (KPAD/2)
    if (idx >= NROWPAD * (KPAD / 2)) return;
    int row = idx / (KPAD / 2), cu = idx % (KPAD / 2);
    unsigned pk = 0;
    if (row < N_NODES && cu < 100) {
        float2 v = *(const float2*)(x + (size_t)row * DIM + cu * 2);
        pk = (unsigned)f2bf(v.x) | ((unsigned)f2bf(v.y) << 16);
    }
    *(unsigned*)(o + (size_t)idx * 2) = pk;
}

// wb[r][b][0..3] = bf16(w[r][b][.][.]) packed 8B per block (w00,w01),(w10,w11)
__global__ void prep_wb(const float* __restrict__ w, unsigned short* __restrict__ o) {
    int idx = blockIdx.x * blockDim.x + threadIdx.x;   // over NRELS*NBLK
    if (idx >= NRELS * NBLK) return;
    float4 v = *(const float4*)(w + (size_t)idx * 4);
    unsigned lo = (unsigned)f2bf(v.x) | ((unsigned)f2bf(v.y) << 16);
    unsigned hi = (unsigned)f2bf(v.z) | ((unsigned)f2bf(v.w) << 16);
    *(uint2*)(o + (size_t)idx * 4) = make_uint2(lo, hi);
}

// ---------------------------------------------------------------- weight prep (fragment-packed bf16, 8 nt)
__global__ void prep_fragT(const float* __restrict__ w, unsigned short* __restrict__ o) {
    int idx = blockIdx.x * blockDim.x + threadIdx.x;
    if (idx >= NFRAG8) return;
    int l = idx & 63;
    int ks = (idx >> 6) % 14;
    int nt = idx / (14 * 64);
    int n  = nt * 32 + (l & 31);
    int k0 = ks * 16 + (l >> 5) * 8;
    unsigned short v[8];
    #pragma unroll
    for (int j = 0; j < 8; ++j) {
        int k = k0 + j;
        v[j] = f2bf((n < DIM && k < DIM) ? w[k * DIM + n] : 0.0f);
    }
    *(uint4*)(o + (size_t)idx * 8) = *(uint4*)v;
}
__global__ void prep_frag(const float* __restrict__ w, unsigned short* __restrict__ o) {
    int idx = blockIdx.x * blockDim.x + threadIdx.x;
    if (idx >= NFRAG8) return;
    int l = idx & 63;
    int ks = (idx >> 6) % 14;
    int nt = idx / (14 * 64);
    int n  = nt * 32 + (l & 31);
    int k0 = ks * 16 + (l >> 5) * 8;
    unsigned short v[8];
    #pragma unroll
    for (int j = 0; j < 8; ++j) {
        int k = k0 + j;
        v[j] = f2bf((n < DIM && k < DIM) ? w[n * DIM + k] : 0.0f);
    }
    *(uint4*)(o + (size_t)idx * 8) = *(uint4*)v;
}

// ---------------------------------------------------------------- gather: 2 blocks/lane, 4-edge pipeline
// lane l<50 owns blocks {2l, 2l+1}: 8B x-load + 16B w-load per edge.
#define GL(QQ, XU, WU)                                                  \
    { int s_ = uread(sv, (QQ)); int r_ = uread(rv, (QQ));               \
      XU = *(const uint2*)(x  + (size_t)s_ * KPAD + xoff);              \
      WU = *(const uint4*)(wb + (size_t)r_ * (NBLK * 4) + woff); }

#define CMP(XU, WU, M0, M1, M2, M3)                                     \
    { float x0 = bflo(XU.x), x1 = bfhi(XU.x);                           \
      float x2 = bflo(XU.y), x3 = bfhi(XU.y);                           \
      M0 += x0 * bflo(WU.x) + x1 * bflo(WU.y);                          \
      M1 += x0 * bfhi(WU.x) + x1 * bfhi(WU.y);                          \
      M2 += x2 * bflo(WU.z) + x3 * bflo(WU.w);                          \
      M3 += x2 * bfhi(WU.z) + x3 * bfhi(WU.w); }

__global__ __launch_bounds__(256) void gatherB(
        const unsigned short* __restrict__ x,    // [NROWPAD][KPAD] bf16
        const int2*  __restrict__ se,
        const int*   __restrict__ endpos,
        const int*   __restrict__ degi,
        const unsigned short* __restrict__ wb,   // [R][NBLK][4] bf16
        unsigned short* __restrict__ agg) {      // [N][DIM] bf16
    int node = (blockIdx.x * blockDim.x + threadIdx.x) >> 6;
    int lane = threadIdx.x & 63;
    if (node >= N_NODES) return;
    int deg = __builtin_amdgcn_readfirstlane(degi[node]);
    const bool act = (lane < 50);
    int cl   = act ? lane : 49;                  // clamp idle lanes to valid addrs
    int xoff = 4 * cl;                           // ushort units (8B per lane)
    int woff = 8 * cl;                           // ushort units (16B per lane)

    if (deg == 0) {
        if (act) *(uint2*)(agg + (size_t)node * DIM + 4 * lane) = make_uint2(0u, 0u);
        return;
    }
    int end   = __builtin_amdgcn_readfirstlane(endpos[node]);
    int start = end - deg;

    float m0A = 0.f, m1A = 0.f, m2A = 0.f, m3A = 0.f;
    float m0B = 0.f, m1B = 0.f, m2B = 0.f, m3B = 0.f;

    for (int base = start; base < end; base += 64) {
        int cnt = end - base; if (cnt > 64) cnt = 64;
        int2 sei = se[base + (lane < cnt ? lane : cnt - 1)];
        int sv = sei.x, rv = sei.y;

        uint2 X0 = {0,0}, X1 = {0,0}, X2 = {0,0}, X3 = {0,0};
        uint4 W0 = {0,0,0,0}, W1 = {0,0,0,0}, W2 = {0,0,0,0}, W3 = {0,0,0,0};

        GL(0, X0, W0);
        if (cnt > 1) GL(1, X1, W1);
        if (cnt > 2) GL(2, X2, W2);

        for (int q = 0; q < cnt; q += 4) {
            if (q + 3 < cnt) GL(q + 3, X3, W3);
            CMP(X0, W0, m0A, m1A, m2A, m3A);
            if (q + 4 < cnt) GL(q + 4, X0, W0);
            if (q + 1 < cnt) CMP(X1, W1, m0B, m1B, m2B, m3B);
            if (q + 5 < cnt) GL(q + 5, X1, W1);
            if (q + 2 < cnt) CMP(X2, W2, m0A, m1A, m2A, m3A);
            if (q + 6 < cnt) GL(q + 6, X2, W2);
            if (q + 3 < cnt) CMP(X3, W3, m0B, m1B, m2B, m3B);
        }
    }
    float nrm = 1.0f / (float)deg;
    if (act) {
        unsigned plo = (unsigned)f2bf((m0A + m0B) * nrm) | ((unsigned)f2bf((m1A + m1B) * nrm) << 16);
        unsigned phi = (unsigned)f2bf((m2A + m2B) * nrm) | ((unsigned)f2bf((m3A + m3B) * nrm) << 16);
        *(uint2*)(agg + (size_t)node * DIM + 4 * lane) = make_uint2(plo, phi);
    }
}

// ---------------------------------------------------------------- GEMM1: hb = bf16(tanh(agg1 + x@loop_w1 + b1))
// In-place: xb and hb are the SAME buffer. agg1 is bf16.
__global__ __launch_bounds__(256) void gemm1_kernel(
        unsigned short* xb_hb,                    // [NROWPAD][KPAD] bf16 (in-place)
        const unsigned short* __restrict__ agg1,  // [N][DIM] bf16
        const float* __restrict__ b1,
        const unsigned short* __restrict__ w1f) { // frag-packed loop_w1 (x@w), 8 nt
    __shared__ __align__(16) unsigned short s_a[32 * KPN];
    int row0 = blockIdx.x * 32;
    int tid = threadIdx.x;
    for (int i = tid; i < 32 * 32; i += 256) {
        int rr = i >> 5, ch = i & 31;
        uint4 v = {0, 0, 0, 0};
        if (ch < 28) v = *(const uint4*)(xb_hb + (size_t)(row0 + rr) * KPAD + ch * 8);
        *(uint4*)((char*)s_a + SWZ5(rr, ch * 16)) = v;
    }
    __syncthreads();

    int l = tid & 63, wv = tid >> 6;
    int rl = l & 31, hl = l >> 5;
    int ntlo = wv * 2;
    const unsigned short* wb = w1f + (size_t)(ntlo * 14) * 512 + l * 8;

    f32x16 acc0 = {}, acc1 = {};
    short8 aC  = *(const short8*)((const char*)s_a + SWZ5(rl, (hl * 8) * 2));
    short8 b0C = *(const short8*)(wb);
    short8 b1C = *(const short8*)(wb + 14 * 512);
    #pragma unroll
    for (int ks = 0; ks < 13; ++ks) {
        short8 aN = {}, b0N = {}, b1N = {};
        if (ks < 12) {
            aN  = *(const short8*)((const char*)s_a + SWZ5(rl, ((ks + 1) * 16 + hl * 8) * 2));
            b0N = *(const short8*)(wb + (ks + 1) * 512);
            b1N = *(const short8*)(wb + 14 * 512 + (ks + 1) * 512);
        }
        acc0 = __builtin_amdgcn_mfma_f32_32x32x16_bf16(aC, b0C, acc0, 0, 0, 0);
        acc1 = __builtin_amdgcn_mfma_f32_32x32x16_bf16(aC, b1C, acc1, 0, 0, 0);
        aC = aN; b0C = b0N; b1C = b1N;
    }
    __syncthreads();   // all tile reads done before in-place overwrite

    #pragma unroll
    for (int t = 0; t < 2; ++t) {
        f32x16 ac = t ? acc1 : acc0;
        int gc = (ntlo + t) * 32 + rl;
        if (gc >= KPAD) continue;
        float bias = (gc < DIM) ? b1[gc] : 0.0f;
        #pragma unroll
        for (int r = 0; r < 16; ++r) {
            int gr = row0 + (r & 3) + 8 * (r >> 2) + 4 * hl;
            float v = 0.0f;
            if (gc < DIM && gr < N_NODES)
                v = ac[r] + b2f(agg1[(size_t)gr * DIM + gc]) + bias;
            xb_hb[(size_t)gr * KPAD + gc] = f2bf(tanh_fast(v));
        }
    }
}

// ---------------------------------------------------------------- GEMM2 (fused RNN), 4 waves/tile, branch-free
__global__ __launch_bounds__(256) void gemm2_kernel(
        const unsigned short* __restrict__ hb,
        const unsigned short* __restrict__ agg2,  // [N][DIM] bf16
        const float* __restrict__ b2,
        const unsigned short* __restrict__ w2f,   // frag-packed loop_w2 (x@w), 8 nt
        const unsigned short* __restrict__ h0b,   // [NROWPAD][KPAD] bf16
        const unsigned short* __restrict__ wihf,  // frag-packed W_ih (x@w^T), 8 nt
        const unsigned short* __restrict__ whhf,  // frag-packed W_hh (x@w^T), 8 nt
        const float* __restrict__ b_ih,
        const float* __restrict__ b_hh,
        float* __restrict__ out) {
    __shared__ __align__(16) unsigned short s_a[32 * KPN];
    __shared__ __align__(16) unsigned short t_lds[32 * KPN];
    int row0 = blockIdx.x * 32;
    int tid = threadIdx.x;
    int l = tid & 63, wv = tid >> 6;
    int rl = l & 31, hl = l >> 5;
    int ntlo = wv * 2;

    for (int i = tid; i < 32 * 32; i += 256) {
        int rr = i >> 5, ch = i & 31;
        uint4 v = {0, 0, 0, 0};
        if (ch < 28) v = *(const uint4*)(hb + (size_t)(row0 + rr) * KPAD + ch * 8);
        *(uint4*)((char*)s_a + SWZ5(rr, ch * 16)) = v;
    }
    __syncthreads();

    // ---- phase A
    {
        const unsigned short* wb = w2f + (size_t)(ntlo * 14) * 512 + l * 8;
        f32x16 acc0 = {}, acc1 = {};
        short8 aC  = *(const short8*)((const char*)s_a + SWZ5(rl, (hl * 8) * 2));
        short8 b0C = *(const short8*)(wb);
        short8 b1C = *(const short8*)(wb + 14 * 512);
        #pragma unroll
        for (int ks = 0; ks < 13; ++ks) {
            short8 aN = {}, b0N = {}, b1N = {};
            if (ks < 12) {
                aN  = *(const short8*)((const char*)s_a + SWZ5(rl, ((ks + 1) * 16 + hl * 8) * 2));
                b0N = *(const short8*)(wb + (ks + 1) * 512);
                b1N = *(const short8*)(wb + 14 * 512 + (ks + 1) * 512);
            }
            acc0 = __builtin_amdgcn_mfma_f32_32x32x16_bf16(aC, b0C, acc0, 0, 0, 0);
            acc1 = __builtin_amdgcn_mfma_f32_32x32x16_bf16(aC, b1C, acc1, 0, 0, 0);
            aC = aN; b0C = b0N; b1C = b1N;
        }
        #pragma unroll
        for (int t = 0; t < 2; ++t) {
            f32x16 ac = t ? acc1 : acc0;
            int gc = (ntlo + t) * 32 + rl;
            float bias = (gc < DIM) ? b2[gc] : 0.0f;
            #pragma unroll
            for (int r = 0; r < 16; ++r) {
                int lr = (r & 3) + 8 * (r >> 2) + 4 * hl;
                int gr = row0 + lr;
                float v = 0.0f;
                if (gc < DIM) {
                    v = ac[r] + bias;
                    if (gr < N_NODES) v += b2f(agg2[(size_t)gr * DIM + gc]);
                }
                *(unsigned short*)((char*)t_lds + SWZ5(lr, gc * 2)) = f2bf(v);
            }
        }
    }
    __syncthreads();

    // restage s_a <- h0b (bf16, same layout as hb)
    for (int i = tid; i < 32 * 32; i += 256) {
        int rr = i >> 5, ch = i & 31;
        uint4 v = {0, 0, 0, 0};
        if (ch < 28) v = *(const uint4*)(h0b + (size_t)(row0 + rr) * KPAD + ch * 8);
        *(uint4*)((char*)s_a + SWZ5(rr, ch * 16)) = v;
    }
    __syncthreads();

    // ---- phase B
    {
        const unsigned short* wi = wihf + (size_t)(ntlo * 14) * 512 + l * 8;
        const unsigned short* wh = whhf + (size_t)(ntlo * 14) * 512 + l * 8;
        f32x16 o0 = {}, o1 = {};
        short8 tC  = *(const short8*)((const char*)t_lds + SWZ5(rl, (hl * 8) * 2));
        short8 fC  = *(const short8*)((const char*)s_a  + SWZ5(rl, (hl * 8) * 2));
        short8 i0C = *(const short8*)(wi);
        short8 i1C = *(const short8*)(wi + 14 * 512);
        short8 h0C = *(const short8*)(wh);
        short8 h1C = *(const short8*)(wh + 14 * 512);
        #pragma unroll
        for (int ks = 0; ks < 13; ++ks) {
            short8 tN = {}, fN = {}, i0N = {}, i1N = {}, h0N = {}, h1N = {};
            if (ks < 12) {
                unsigned off = ((ks + 1) * 16 + hl * 8) * 2;
                tN  = *(const short8*)((const char*)t_lds + SWZ5(rl, off));
                fN  = *(const short8*)((const char*)s_a  + SWZ5(rl, off));
                i0N = *(const short8*)(wi + (ks + 1) * 512);
                i1N = *(const short8*)(wi + 14 * 512 + (ks + 1) * 512);
                h0N = *(const short8*)(wh + (ks + 1) * 512);
                h1N = *(const short8*)(wh + 14 * 512 + (ks + 1) * 512);
            }
            o0 = __builtin_amdgcn_mfma_f32_32x32x16_bf16(tC, i0C, o0, 0, 0, 0);
            o0 = __builtin_amdgcn_mfma_f32_32x32x16_bf16(fC, h0C, o0, 0, 0, 0);
            o1 = __builtin_amdgcn_mfma_f32_32x32x16_bf16(tC, i1C, o1, 0, 0, 0);
            o1 = __builtin_amdgcn_mfma_f32_32x32x16_bf16(fC, h1C, o1, 0, 0, 0);
            tC = tN; fC = fN; i0C = i0N; i1C = i1N; h0C = h0N; h1C = h1N;
        }
        #pragma unroll
        for (int t = 0; t < 2; ++t) {
            f32x16 oc = t ? o1 : o0;
            int gc = (ntlo + t) * 32 + rl;
            if (gc >= DIM) continue;
            float bias = b_ih[gc] + b_hh[gc];
            #pragma unroll
            for (int r = 0; r < 16; ++r) {
                int gr = row0 + (r & 3) + 8 * (r >> 2) + 4 * hl;
                if (gr < N_NODES)
                    out[(size_t)gr * DIM + gc] = tanh_fast(oc[r] + bias);
            }
        }
    }
}

// ---------------------------------------------------------------- launch
extern "C" void kernel_launch(void* const* d_in, const int* in_sizes, int n_in,
                              void* d_out, int out_size, void* d_ws, size_t ws_size,
                              hipStream_t stream) {
    const float* node_feat = (const float*)d_in[0];
    const float* dyn_emb   = (const float*)d_in[1];
    const int*   src       = (const int*)  d_in[2];
    const int*   dst       = (const int*)  d_in[3];
    const int*   etypes    = (const int*)  d_in[4];
    const float* w1        = (const float*)d_in[5];
    const float* loop_w1   = (const float*)d_in[6];
    const float* b1        = (const float*)d_in[7];
    const float* w2        = (const float*)d_in[8];
    const float* loop_w2   = (const float*)d_in[9];
    const float* b2        = (const float*)d_in[10];
    const float* W_ih      = (const float*)d_in[11];
    const float* W_hh      = (const float*)d_in[12];
    const float* b_ih      = (const float*)d_in[13];
    const float* b_hh      = (const float*)d_in[14];
    float* out = (float*)d_out;

    // workspace layout (~76 MB)
    int*   degi = (int*)d_ws;                          // 51200
    int*   pos  = degi + 51200;                        // 51200
    int*   bsum = pos  + 51200;                        // 256
    int2*  se   = (int2*)(bsum + 256);                 // 800000 int2 (6.4 MB)
    unsigned short* agg = (unsigned short*)(se + N_EDGES);     // N*DIM bf16 (20 MB)
    unsigned short* hb   = agg  + (size_t)N_NODES * DIM;       // 50048*224 (22.4 MB) — ALSO xb
    unsigned short* h0b  = hb   + (size_t)NROWPAD * KPAD;      // 22.4 MB
    unsigned short* w1f  = h0b  + (size_t)NROWPAD * KPAD;      // NFRAG8*8 each
    unsigned short* w2f  = w1f  + (size_t)NFRAG8 * 8;
    unsigned short* wihf = w2f  + (size_t)NFRAG8 * 8;
    unsigned short* whhf = wihf + (size_t)NFRAG8 * 8;
    unsigned short* w1b  = whhf + (size_t)NFRAG8 * 8;          // NRELS*NBLK*4 (184 KB)
    unsigned short* w2b  = w1b  + (size_t)NRELS * NBLK * 4;

    hipMemsetAsync(degi, 0, 51200 * sizeof(int), stream);

    // CSR build
    deg_int_kernel<<<(N_EDGES + 255) / 256, 256, 0, stream>>>(dst, degi);
    scanA<<<NB_SCAN, 256, 0, stream>>>(degi, pos, bsum);
    scanB<<<1, 256, 0, stream>>>(bsum);
    scanC<<<NB_SCAN, 256, 0, stream>>>(pos, bsum);
    fill_kernel<<<(N_EDGES + 255) / 256, 256, 0, stream>>>(src, dst, etypes, pos, se);

    // bf16 prep
    prep_xb<<<(NROWPAD * (KPAD / 2) + 255) / 256, 256, 0, stream>>>(node_feat, hb);
    prep_xb<<<(NROWPAD * (KPAD / 2) + 255) / 256, 256, 0, stream>>>(dyn_emb, h0b);
    prep_wb<<<(NRELS * NBLK + 255) / 256, 256, 0, stream>>>(w1, w1b);
    prep_wb<<<(NRELS * NBLK + 255) / 256, 256, 0, stream>>>(w2, w2b);
    prep_fragT<<<(NFRAG8 + 255) / 256, 256, 0, stream>>>(loop_w1, w1f);
    prep_fragT<<<(NFRAG8 + 255) / 256, 256, 0, stream>>>(loop_w2, w2f);
    prep_frag <<<(NFRAG8 + 255) / 256, 256, 0, stream>>>(W_ih, wihf);
    prep_frag <<<(NFRAG8 + 255) / 256, 256, 0, stream>>>(W_hh, whhf);

    // ---- layer 1 (gather reads xb=hb; gemm1 overwrites it in place with h)
    gatherB<<<(N_NODES * 64 + 255) / 256, 256, 0, stream>>>(
        hb, se, pos, degi, w1b, agg);
    gemm1_kernel<<<(N_NODES + 31) / 32, 256, 0, stream>>>(
        hb, agg, b1, w1f);

    // ---- layer 2
    gatherB<<<(N_NODES * 64 + 255) / 256, 256, 0, stream>>>(
        hb, se, pos, degi, w2b, agg);

    // ---- fused layer-2 dense + RNN cell
    gemm2_kernel<<<(N_NODES + 31) / 32, 256, 0, stream>>>(
        hb, agg, b2, w2f, h0b, wihf, whhf, b_ih, b_hh, out);
}

// Round 9
// 348.235 us; speedup vs baseline: 1.5656x; 1.0081x over previous
//
#include <hip/hip_runtime.h>

#define N_NODES 50000
#define N_EDGES 800000
#define DIM     200
#define NBLK    100   // B blocks of S=2
#define NRELS   230
#define NB_SCAN 196   // ceil(N_NODES/256)
#define KPAD    224   // feature-row stride (bf16 buffers)
#define KPN     256   // gemm output-column pad (8 nt of 32)
#define NROWPAD 50048
#define NFRAG8  (8 * 14 * 64)   // fragment-packed weights: 8 nt x 14 ks x 64 lanes (x8 bf16)

typedef __attribute__((ext_vector_type(8)))  short short8;
typedef __attribute__((ext_vector_type(16))) float f32x16;

__device__ __forceinline__ unsigned short f2bf(float f) {
    unsigned u = __float_as_uint(f);
    u += 0x7fffu + ((u >> 16) & 1u);        // RNE (inputs finite)
    return (unsigned short)(u >> 16);
}

__device__ __forceinline__ float bflo(unsigned u) { return __uint_as_float(u << 16); }
__device__ __forceinline__ float bfhi(unsigned u) { return __uint_as_float(u & 0xffff0000u); }
__device__ __forceinline__ float b2f(unsigned short u) { return __uint_as_float((unsigned)u << 16); }

__device__ __forceinline__ float tanh_fast(float x) {
    float xa = fminf(fmaxf(x, -15.0f), 15.0f);
    float e = __expf(2.0f * xa);
    return (e - 1.0f) / (e + 1.0f);
}

__device__ __forceinline__ int uread(int v, int l) {
    return __builtin_amdgcn_readlane(v, l);
}

// ---- bf16 dot2: 1 instruction for a0*b0+a1*b1+c when available
#if __has_builtin(__builtin_amdgcn_fdot2_f32_bf16)
typedef __bf16 bf16x2 __attribute__((ext_vector_type(2)));
__device__ __forceinline__ float dot2bf(unsigned a, unsigned b, float c) {
    return __builtin_amdgcn_fdot2_f32_bf16(
        __builtin_bit_cast(bf16x2, a), __builtin_bit_cast(bf16x2, b), c, false);
}
#define CMP(XU, WU, M0, M1, M2, M3)                                     \
    { M0 = dot2bf(XU.x, WU.x, M0); M1 = dot2bf(XU.x, WU.y, M1);         \
      M2 = dot2bf(XU.y, WU.z, M2); M3 = dot2bf(XU.y, WU.w, M3); }
#else
// fallback: manual unpack (weight words are (w00,w10),(w01,w11))
#define CMP(XU, WU, M0, M1, M2, M3)                                     \
    { float x0 = bflo(XU.x), x1 = bfhi(XU.x);                           \
      float x2 = bflo(XU.y), x3 = bfhi(XU.y);                           \
      M0 += x0 * bflo(WU.x) + x1 * bfhi(WU.x);                          \
      M1 += x0 * bflo(WU.y) + x1 * bfhi(WU.y);                          \
      M2 += x2 * bflo(WU.z) + x3 * bfhi(WU.z);                          \
      M3 += x2 * bflo(WU.w) + x3 * bfhi(WU.w); }
#endif

// LDS swizzle for 512B-stride rows, 16B-granular access
#define SWZ5(rr, off) ((unsigned)((rr) * 512 + (off)) ^ ((unsigned)((rr) & 15) << 4))

// ---------------------------------------------------------------- CSR build
__global__ void deg_int_kernel(const int* __restrict__ dst, int* __restrict__ degi) {
    int e = blockIdx.x * blockDim.x + threadIdx.x;
    if (e < N_EDGES) atomicAdd(&degi[dst[e]], 1);
}

__global__ __launch_bounds__(256) void scanA(const int* __restrict__ degi,
                                             int* __restrict__ pos,
                                             int* __restrict__ bsum) {
    __shared__ int tmp[256];
    int t = threadIdx.x;
    int g = blockIdx.x * 256 + t;
    int v = (g < N_NODES) ? degi[g] : 0;
    tmp[t] = v;
    __syncthreads();
    for (int off = 1; off < 256; off <<= 1) {
        int xv = (t >= off) ? tmp[t - off] : 0;
        __syncthreads();
        tmp[t] += xv;
        __syncthreads();
    }
    if (g < N_NODES) pos[g] = tmp[t] - v;
    if (t == 255) bsum[blockIdx.x] = tmp[255];
}

__global__ __launch_bounds__(256) void scanB(int* __restrict__ bsum) {
    __shared__ int tmp[256];
    int t = threadIdx.x;
    int v = (t < NB_SCAN) ? bsum[t] : 0;
    tmp[t] = v;
    __syncthreads();
    for (int off = 1; off < 256; off <<= 1) {
        int xv = (t >= off) ? tmp[t - off] : 0;
        __syncthreads();
        tmp[t] += xv;
        __syncthreads();
    }
    if (t < NB_SCAN) bsum[t] = tmp[t] - v;
}

__global__ __launch_bounds__(256) void scanC(int* __restrict__ pos, const int* __restrict__ bsum) {
    int g = blockIdx.x * 256 + threadIdx.x;
    if (g < N_NODES) pos[g] += bsum[blockIdx.x];
}

// fill: se[slot] = src | (etype << 16)  (src < 2^16, etype < 2^8)
__global__ void fill_kernel(const int* __restrict__ src, const int* __restrict__ dst,
                            const int* __restrict__ et,
                            int* __restrict__ pos, int* __restrict__ se) {
    int e = blockIdx.x * blockDim.x + threadIdx.x;
    if (e < N_EDGES) {
        int d = dst[e];
        int slot = atomicAdd(&pos[d], 1);
        se[slot] = src[e] | (et[e] << 16);
    }
}

// ---------------------------------------------------------------- feature / relation-weight bf16 prep
__global__ void prep_xb(const float* __restrict__ x, unsigned short* __restrict__ o) {
    int idx = blockIdx.x * blockDim.x + threadIdx.x;   // over NROWPAD * (KPAD/2)
    if (idx >= NROWPAD * (KPAD / 2)) return;
    int row = idx / (KPAD / 2), cu = idx % (KPAD / 2);
    unsigned pk = 0;
    if (row < N_NODES && cu < 100) {
        float2 v = *(const float2*)(x + (size_t)row * DIM + cu * 2);
        pk = (unsigned)f2bf(v.x) | ((unsigned)f2bf(v.y) << 16);
    }
    *(unsigned*)(o + (size_t)idx * 2) = pk;
}

// wb[r][b]: word0 = (w00,w10), word1 = (w01,w11)  — dot2-ready column pairs
__global__ void prep_wb(const float* __restrict__ w, unsigned short* __restrict__ o) {
    int idx = blockIdx.x * blockDim.x + threadIdx.x;   // over NRELS*NBLK
    if (idx >= NRELS * NBLK) return;
    float4 v = *(const float4*)(w + (size_t)idx * 4);  // w00,w01,w10,w11
    unsigned c0 = (unsigned)f2bf(v.x) | ((unsigned)f2bf(v.z) << 16);
    unsigned c1 = (unsigned)f2bf(v.y) | ((unsigned)f2bf(v.w) << 16);
    *(uint2*)(o + (size_t)idx * 4) = make_uint2(c0, c1);
}

// ---------------------------------------------------------------- weight prep (fragment-packed bf16, 8 nt)
__global__ void prep_fragT(const float* __restrict__ w, unsigned short* __restrict__ o) {
    int idx = blockIdx.x * blockDim.x + threadIdx.x;
    if (idx >= NFRAG8) return;
    int l = idx & 63;
    int ks = (idx >> 6) % 14;
    int nt = idx / (14 * 64);
    int n  = nt * 32 + (l & 31);
    int k0 = ks * 16 + (l >> 5) * 8;
    unsigned short v[8];
    #pragma unroll
    for (int j = 0; j < 8; ++j) {
        int k = k0 + j;
        v[j] = f2bf((n < DIM && k < DIM) ? w[k * DIM + n] : 0.0f);
    }
    *(uint4*)(o + (size_t)idx * 8) = *(uint4*)v;
}
__global__ void prep_frag(const float* __restrict__ w, unsigned short* __restrict__ o) {
    int idx = blockIdx.x * blockDim.x + threadIdx.x;
    if (idx >= NFRAG8) return;
    int l = idx & 63;
    int ks = (idx >> 6) % 14;
    int nt = idx / (14 * 64);
    int n  = nt * 32 + (l & 31);
    int k0 = ks * 16 + (l >> 5) * 8;
    unsigned short v[8];
    #pragma unroll
    for (int j = 0; j < 8; ++j) {
        int k = k0 + j;
        v[j] = f2bf((n < DIM && k < DIM) ? w[n * DIM + k] : 0.0f);
    }
    *(uint4*)(o + (size_t)idx * 8) = *(uint4*)v;
}

// ---------------------------------------------------------------- gather: 2 blocks/lane, 4-edge pipeline
// lane l<50 owns blocks {2l, 2l+1}: 8B x-load + 16B w-load per edge; 1 readlane/edge.
#define GL(QQ, XU, WU)                                                  \
    { int p_ = uread(sv, (QQ)); int s_ = p_ & 0xffff; int r_ = p_ >> 16;\
      XU = *(const uint2*)(x  + (size_t)s_ * KPAD + xoff);              \
      WU = *(const uint4*)(wb + (size_t)r_ * (NBLK * 4) + woff); }

__global__ __launch_bounds__(256) void gatherB(
        const unsigned short* __restrict__ x,    // [NROWPAD][KPAD] bf16
        const int*   __restrict__ se,            // packed (src | et<<16), CSR order
        const int*   __restrict__ endpos,
        const int*   __restrict__ degi,
        const unsigned short* __restrict__ wb,   // [R][NBLK][4] bf16 (column pairs)
        unsigned short* __restrict__ agg) {      // [N][DIM] bf16
    int node = (blockIdx.x * blockDim.x + threadIdx.x) >> 6;
    int lane = threadIdx.x & 63;
    if (node >= N_NODES) return;
    int deg = __builtin_amdgcn_readfirstlane(degi[node]);
    const bool act = (lane < 50);
    int cl   = act ? lane : 49;                  // clamp idle lanes to valid addrs
    int xoff = 4 * cl;                           // ushort units (8B per lane)
    int woff = 8 * cl;                           // ushort units (16B per lane)

    if (deg == 0) {
        if (act) *(uint2*)(agg + (size_t)node * DIM + 4 * lane) = make_uint2(0u, 0u);
        return;
    }
    int end   = __builtin_amdgcn_readfirstlane(endpos[node]);
    int start = end - deg;

    float m0A = 0.f, m1A = 0.f, m2A = 0.f, m3A = 0.f;
    float m0B = 0.f, m1B = 0.f, m2B = 0.f, m3B = 0.f;

    for (int base = start; base < end; base += 64) {
        int cnt = end - base; if (cnt > 64) cnt = 64;
        int sv = se[base + (lane < cnt ? lane : cnt - 1)];

        uint2 X0 = {0,0}, X1 = {0,0}, X2 = {0,0}, X3 = {0,0};
        uint4 W0 = {0,0,0,0}, W1 = {0,0,0,0}, W2 = {0,0,0,0}, W3 = {0,0,0,0};

        GL(0, X0, W0);
        if (cnt > 1) GL(1, X1, W1);
        if (cnt > 2) GL(2, X2, W2);

        for (int q = 0; q < cnt; q += 4) {
            if (q + 3 < cnt) GL(q + 3, X3, W3);
            CMP(X0, W0, m0A, m1A, m2A, m3A);
            if (q + 4 < cnt) GL(q + 4, X0, W0);
            if (q + 1 < cnt) CMP(X1, W1, m0B, m1B, m2B, m3B);
            if (q + 5 < cnt) GL(q + 5, X1, W1);
            if (q + 2 < cnt) CMP(X2, W2, m0A, m1A, m2A, m3A);
            if (q + 6 < cnt) GL(q + 6, X2, W2);
            if (q + 3 < cnt) CMP(X3, W3, m0B, m1B, m2B, m3B);
        }
    }
    float nrm = 1.0f / (float)deg;
    if (act) {
        unsigned plo = (unsigned)f2bf((m0A + m0B) * nrm) | ((unsigned)f2bf((m1A + m1B) * nrm) << 16);
        unsigned phi = (unsigned)f2bf((m2A + m2B) * nrm) | ((unsigned)f2bf((m3A + m3B) * nrm) << 16);
        *(uint2*)(agg + (size_t)node * DIM + 4 * lane) = make_uint2(plo, phi);
    }
}

// ---------------------------------------------------------------- GEMM1: hb = bf16(tanh(agg1 + x@loop_w1 + b1))
// In-place: xb and hb are the SAME buffer. agg1 is bf16.
__global__ __launch_bounds__(256) void gemm1_kernel(
        unsigned short* xb_hb,                    // [NROWPAD][KPAD] bf16 (in-place)
        const unsigned short* __restrict__ agg1,  // [N][DIM] bf16
        const float* __restrict__ b1,
        const unsigned short* __restrict__ w1f) { // frag-packed loop_w1 (x@w), 8 nt
    __shared__ __align__(16) unsigned short s_a[32 * KPN];
    int row0 = blockIdx.x * 32;
    int tid = threadIdx.x;
    for (int i = tid; i < 32 * 32; i += 256) {
        int rr = i >> 5, ch = i & 31;
        uint4 v = {0, 0, 0, 0};
        if (ch < 28) v = *(const uint4*)(xb_hb + (size_t)(row0 + rr) * KPAD + ch * 8);
        *(uint4*)((char*)s_a + SWZ5(rr, ch * 16)) = v;
    }
    __syncthreads();

    int l = tid & 63, wv = tid >> 6;
    int rl = l & 31, hl = l >> 5;
    int ntlo = wv * 2;
    const unsigned short* wb = w1f + (size_t)(ntlo * 14) * 512 + l * 8;

    f32x16 acc0 = {}, acc1 = {};
    short8 aC  = *(const short8*)((const char*)s_a + SWZ5(rl, (hl * 8) * 2));
    short8 b0C = *(const short8*)(wb);
    short8 b1C = *(const short8*)(wb + 14 * 512);
    #pragma unroll
    for (int ks = 0; ks < 13; ++ks) {
        short8 aN = {}, b0N = {}, b1N = {};
        if (ks < 12) {
            aN  = *(const short8*)((const char*)s_a + SWZ5(rl, ((ks + 1) * 16 + hl * 8) * 2));
            b0N = *(const short8*)(wb + (ks + 1) * 512);
            b1N = *(const short8*)(wb + 14 * 512 + (ks + 1) * 512);
        }
        acc0 = __builtin_amdgcn_mfma_f32_32x32x16_bf16(aC, b0C, acc0, 0, 0, 0);
        acc1 = __builtin_amdgcn_mfma_f32_32x32x16_bf16(aC, b1C, acc1, 0, 0, 0);
        aC = aN; b0C = b0N; b1C = b1N;
    }
    __syncthreads();   // all tile reads done before in-place overwrite

    #pragma unroll
    for (int t = 0; t < 2; ++t) {
        f32x16 ac = t ? acc1 : acc0;
        int gc = (ntlo + t) * 32 + rl;
        if (gc >= KPAD) continue;
        float bias = (gc < DIM) ? b1[gc] : 0.0f;
        #pragma unroll
        for (int r = 0; r < 16; ++r) {
            int gr = row0 + (r & 3) + 8 * (r >> 2) + 4 * hl;
            float v = 0.0f;
            if (gc < DIM && gr < N_NODES)
                v = ac[r] + b2f(agg1[(size_t)gr * DIM + gc]) + bias;
            xb_hb[(size_t)gr * KPAD + gc] = f2bf(tanh_fast(v));
        }
    }
}

// ---------------------------------------------------------------- GEMM2 (fused RNN), 4 waves/tile, branch-free
__global__ __launch_bounds__(256) void gemm2_kernel(
        const unsigned short* __restrict__ hb,
        const unsigned short* __restrict__ agg2,  // [N][DIM] bf16
        const float* __restrict__ b2,
        const unsigned short* __restrict__ w2f,   // frag-packed loop_w2 (x@w), 8 nt
        const unsigned short* __restrict__ h0b,   // [NROWPAD][KPAD] bf16
        const unsigned short* __restrict__ wihf,  // frag-packed W_ih (x@w^T), 8 nt
        const unsigned short* __restrict__ whhf,  // frag-packed W_hh (x@w^T), 8 nt
        const float* __restrict__ b_ih,
        const float* __restrict__ b_hh,
        float* __restrict__ out) {
    __shared__ __align__(16) unsigned short s_a[32 * KPN];
    __shared__ __align__(16) unsigned short t_lds[32 * KPN];
    int row0 = blockIdx.x * 32;
    int tid = threadIdx.x;
    int l = tid & 63, wv = tid >> 6;
    int rl = l & 31, hl = l >> 5;
    int ntlo = wv * 2;

    for (int i = tid; i < 32 * 32; i += 256) {
        int rr = i >> 5, ch = i & 31;
        uint4 v = {0, 0, 0, 0};
        if (ch < 28) v = *(const uint4*)(hb + (size_t)(row0 + rr) * KPAD + ch * 8);
        *(uint4*)((char*)s_a + SWZ5(rr, ch * 16)) = v;
    }
    __syncthreads();

    // ---- phase A
    {
        const unsigned short* wb = w2f + (size_t)(ntlo * 14) * 512 + l * 8;
        f32x16 acc0 = {}, acc1 = {};
        short8 aC  = *(const short8*)((const char*)s_a + SWZ5(rl, (hl * 8) * 2));
        short8 b0C = *(const short8*)(wb);
        short8 b1C = *(const short8*)(wb + 14 * 512);
        #pragma unroll
        for (int ks = 0; ks < 13; ++ks) {
            short8 aN = {}, b0N = {}, b1N = {};
            if (ks < 12) {
                aN  = *(const short8*)((const char*)s_a + SWZ5(rl, ((ks + 1) * 16 + hl * 8) * 2));
                b0N = *(const short8*)(wb + (ks + 1) * 512);
                b1N = *(const short8*)(wb + 14 * 512 + (ks + 1) * 512);
            }
            acc0 = __builtin_amdgcn_mfma_f32_32x32x16_bf16(aC, b0C, acc0, 0, 0, 0);
            acc1 = __builtin_amdgcn_mfma_f32_32x32x16_bf16(aC, b1C, acc1, 0, 0, 0);
            aC = aN; b0C = b0N; b1C = b1N;
        }
        #pragma unroll
        for (int t = 0; t < 2; ++t) {
            f32x16 ac = t ? acc1 : acc0;
            int gc = (ntlo + t) * 32 + rl;
            float bias = (gc < DIM) ? b2[gc] : 0.0f;
            #pragma unroll
            for (int r = 0; r < 16; ++r) {
                int lr = (r & 3) + 8 * (r >> 2) + 4 * hl;
                int gr = row0 + lr;
                float v = 0.0f;
                if (gc < DIM) {
                    v = ac[r] + bias;
                    if (gr < N_NODES) v += b2f(agg2[(size_t)gr * DIM + gc]);
                }
                *(unsigned short*)((char*)t_lds + SWZ5(lr, gc * 2)) = f2bf(v);
            }
        }
    }
    __syncthreads();

    // restage s_a <- h0b (bf16, same layout as hb)
    for (int i = tid; i < 32 * 32; i += 256) {
        int rr = i >> 5, ch = i & 31;
        uint4 v = {0, 0, 0, 0};
        if (ch < 28) v = *(const uint4*)(h0b + (size_t)(row0 + rr) * KPAD + ch * 8);
        *(uint4*)((char*)s_a + SWZ5(rr, ch * 16)) = v;
    }
    __syncthreads();

    // ---- phase B
    {
        const unsigned short* wi = wihf + (size_t)(ntlo * 14) * 512 + l * 8;
        const unsigned short* wh = whhf + (size_t)(ntlo * 14) * 512 + l * 8;
        f32x16 o0 = {}, o1 = {};
        short8 tC  = *(const short8*)((const char*)t_lds + SWZ5(rl, (hl * 8) * 2));
        short8 fC  = *(const short8*)((const char*)s_a  + SWZ5(rl, (hl * 8) * 2));
        short8 i0C = *(const short8*)(wi);
        short8 i1C = *(const short8*)(wi + 14 * 512);
        short8 h0C = *(const short8*)(wh);
        short8 h1C = *(const short8*)(wh + 14 * 512);
        #pragma unroll
        for (int ks = 0; ks < 13; ++ks) {
            short8 tN = {}, fN = {}, i0N = {}, i1N = {}, h0N = {}, h1N = {};
            if (ks < 12) {
                unsigned off = ((ks + 1) * 16 + hl * 8) * 2;
                tN  = *(const short8*)((const char*)t_lds + SWZ5(rl, off));
                fN  = *(const short8*)((const char*)s_a  + SWZ5(rl, off));
                i0N = *(const short8*)(wi + (ks + 1) * 512);
                i1N = *(const short8*)(wi + 14 * 512 + (ks + 1) * 512);
                h0N = *(const short8*)(wh + (ks + 1) * 512);
                h1N = *(const short8*)(wh + 14 * 512 + (ks + 1) * 512);
            }
            o0 = __builtin_amdgcn_mfma_f32_32x32x16_bf16(tC, i0C, o0, 0, 0, 0);
            o0 = __builtin_amdgcn_mfma_f32_32x32x16_bf16(fC, h0C, o0, 0, 0, 0);
            o1 = __builtin_amdgcn_mfma_f32_32x32x16_bf16(tC, i1C, o1, 0, 0, 0);
            o1 = __builtin_amdgcn_mfma_f32_32x32x16_bf16(fC, h1C, o1, 0, 0, 0);
            tC = tN; fC = fN; i0C = i0N; i1C = i1N; h0C = h0N; h1C = h1N;
        }
        #pragma unroll
        for (int t = 0; t < 2; ++t) {
            f32x16 oc = t ? o1 : o0;
            int gc = (ntlo + t) * 32 + rl;
            if (gc >= DIM) continue;
            float bias = b_ih[gc] + b_hh[gc];
            #pragma unroll
            for (int r = 0; r < 16; ++r) {
                int gr = row0 + (r & 3) + 8 * (r >> 2) + 4 * hl;
                if (gr < N_NODES)
                    out[(size_t)gr * DIM + gc] = tanh_fast(oc[r] + bias);
            }
        }
    }
}

// ---------------------------------------------------------------- launch
extern "C" void kernel_launch(void* const* d_in, const int* in_sizes, int n_in,
                              void* d_out, int out_size, void* d_ws, size_t ws_size,
                              hipStream_t stream) {
    const float* node_feat = (const float*)d_in[0];
    const float* dyn_emb   = (const float*)d_in[1];
    const int*   src       = (const int*)  d_in[2];
    const int*   dst       = (const int*)  d_in[3];
    const int*   etypes    = (const int*)  d_in[4];
    const float* w1        = (const float*)d_in[5];
    const float* loop_w1   = (const float*)d_in[6];
    const float* b1        = (const float*)d_in[7];
    const float* w2        = (const float*)d_in[8];
    const float* loop_w2   = (const float*)d_in[9];
    const float* b2        = (const float*)d_in[10];
    const float* W_ih      = (const float*)d_in[11];
    const float* W_hh      = (const float*)d_in[12];
    const float* b_ih      = (const float*)d_in[13];
    const float* b_hh      = (const float*)d_in[14];
    float* out = (float*)d_out;

    // workspace layout (~73 MB)
    int*   degi = (int*)d_ws;                          // 51200
    int*   pos  = degi + 51200;                        // 51200
    int*   bsum = pos  + 51200;                        // 256
    int*   se   = bsum + 256;                          // 800000 int (3.2 MB)
    unsigned short* agg = (unsigned short*)(se + N_EDGES);     // N*DIM bf16 (20 MB)
    unsigned short* hb   = agg  + (size_t)N_NODES * DIM;       // 50048*224 (22.4 MB) — ALSO xb
    unsigned short* h0b  = hb   + (size_t)NROWPAD * KPAD;      // 22.4 MB
    unsigned short* w1f  = h0b  + (size_t)NROWPAD * KPAD;      // NFRAG8*8 each
    unsigned short* w2f  = w1f  + (size_t)NFRAG8 * 8;
    unsigned short* wihf = w2f  + (size_t)NFRAG8 * 8;
    unsigned short* whhf = wihf + (size_t)NFRAG8 * 8;
    unsigned short* w1b  = whhf + (size_t)NFRAG8 * 8;          // NRELS*NBLK*4 (184 KB)
    unsigned short* w2b  = w1b  + (size_t)NRELS * NBLK * 4;

    hipMemsetAsync(degi, 0, 51200 * sizeof(int), stream);

    // CSR build
    deg_int_kernel<<<(N_EDGES + 255) / 256, 256, 0, stream>>>(dst, degi);
    scanA<<<NB_SCAN, 256, 0, stream>>>(degi, pos, bsum);
    scanB<<<1, 256, 0, stream>>>(bsum);
    scanC<<<NB_SCAN, 256, 0, stream>>>(pos, bsum);
    fill_kernel<<<(N_EDGES + 255) / 256, 256, 0, stream>>>(src, dst, etypes, pos, se);

    // bf16 prep
    prep_xb<<<(NROWPAD * (KPAD / 2) + 255) / 256, 256, 0, stream>>>(node_feat, hb);
    prep_xb<<<(NROWPAD * (KPAD / 2) + 255) / 256, 256, 0, stream>>>(dyn_emb, h0b);
    prep_wb<<<(NRELS * NBLK + 255) / 256, 256, 0, stream>>>(w1, w1b);
    prep_wb<<<(NRELS * NBLK + 255) / 256, 256, 0, stream>>>(w2, w2b);
    prep_fragT<<<(NFRAG8 + 255) / 256, 256, 0, stream>>>(loop_w1, w1f);
    prep_fragT<<<(NFRAG8 + 255) / 256, 256, 0, stream>>>(loop_w2, w2f);
    prep_frag <<<(NFRAG8 + 255) / 256, 256, 0, stream>>>(W_ih, wihf);
    prep_frag <<<(NFRAG8 + 255) / 256, 256, 0, stream>>>(W_hh, whhf);

    // ---- layer 1 (gather reads xb=hb; gemm1 overwrites it in place with h)
    gatherB<<<(N_NODES * 64 + 255) / 256, 256, 0, stream>>>(
        hb, se, pos, degi, w1b, agg);
    gemm1_kernel<<<(N_NODES + 31) / 32, 256, 0, stream>>>(
        hb, agg, b1, w1f);

    // ---- layer 2
    gatherB<<<(N_NODES * 64 + 255) / 256, 256, 0, stream>>>(
        hb, se, pos, degi, w2b, agg);

    // ---- fused layer-2 dense + RNN cell
    gemm2_kernel<<<(N_NODES + 31) / 32, 256, 0, stream>>>(
        hb, agg, b2, w2f, h0b, wihf, whhf, b_ih, b_hh, out);
}